// Round 11
// baseline (703.224 us; speedup 1.0000x reference)
//
#include <hip/hip_runtime.h>

typedef unsigned short ushort_t;
typedef unsigned int   uint_t;
typedef int   i32x4 __attribute__((ext_vector_type(4)));

typedef __attribute__((address_space(3))) void lds_void_t;
typedef __attribute__((address_space(1))) void gbl_void_t;

#define NN 8192
#define HH 128
#define KS 8          // K-split factor
#define KLEN 1024     // K elements per split slice
#define NTQ 16        // K-tiles per block (KLEN / 64, i8 BK=64)

__device__ __forceinline__ ushort_t f2bf(float x) {
    uint_t u = __float_as_uint(x);
    u += 0x7fffu + ((u >> 16) & 1u);          // RNE
    return (ushort_t)(u >> 16);
}
__device__ __forceinline__ float bf2f(uint_t lo16) { return __uint_as_float(lo16 << 16); }
__device__ __forceinline__ float leaky(float x) { return x > 0.f ? x : 0.01f * x; }

// ---------------------------------------------------------------------------
// K0: adj f32 -> i8 + row sums. Block 0 also zeroes cmaxb (replaces memset).
// REP: idempotent diagnostic repetition.
template<int REP>
__global__ __launch_bounds__(256) void conv_rowsum(const float* __restrict__ adj,
    char* __restrict__ adjq, float* __restrict__ s, float* __restrict__ rinv,
    float* __restrict__ cmaxb)
{
    const int i = blockIdx.x;
    if (i == 0) {
        ((float4*)cmaxb)[threadIdx.x] = float4{0.f, 0.f, 0.f, 0.f};  // 1024 floats
    }
    for (int rep = 0; rep < REP; ++rep) {
        const float4* arow = (const float4*)(adj + ((size_t)i << 13));
        uint_t* brow = (uint_t*)(adjq + ((size_t)i << 13));
        float partial = 0.f;
        for (int t = threadIdx.x; t < 2048; t += 256) {
            const float4 v = arow[t];
            partial += (v.x + v.y) + (v.z + v.w);
            const uint_t q0 = (uint_t)__float2int_rn(v.x * 127.f);
            const uint_t q1 = (uint_t)__float2int_rn(v.y * 127.f);
            const uint_t q2 = (uint_t)__float2int_rn(v.z * 127.f);
            const uint_t q3 = (uint_t)__float2int_rn(v.w * 127.f);
            brow[t] = q0 | (q1 << 8) | (q2 << 16) | (q3 << 24);
        }
        #pragma unroll
        for (int off = 32; off; off >>= 1) partial += __shfl_xor(partial, off);
        __shared__ float ps[4];
        if ((threadIdx.x & 63) == 0) ps[threadIdx.x >> 6] = partial;
        __syncthreads();
        if (threadIdx.x == 0) {
            const float tot = (ps[0] + ps[1]) + (ps[2] + ps[3]);
            s[i]    = rsqrtf(tot + 1.0f);
            rinv[i] = 1.0f / tot;
        }
        __syncthreads();
    }
}

// ---------------------------------------------------------------------------
// K1: per-column max of |b| for level-1 B.
__global__ __launch_bounds__(256) void preMax(const float* __restrict__ u,
    const float* __restrict__ v, const float* __restrict__ s, const float* __restrict__ rinv,
    float* __restrict__ cmax)
{
    const int j0 = (blockIdx.x & 127) << 6;
    const int c0 = (blockIdx.x >> 7) << 6;
    __shared__ uint_t cm[64];
    if (threadIdx.x < 64) cm[threadIdx.x] = 0;
    __syncthreads();
    const int tx = threadIdx.x & 63;
    const int ty = threadIdx.x >> 6;
    float m = 0.f;
    #pragma unroll
    for (int rr = 0; rr < 16; ++rr) {
        const int j = j0 + ty + (rr << 2);
        const int c = c0 + tx;
        const float val = (c < 128) ? s[j] * u[((size_t)j << 7) + c]
                                    : rinv[j] * v[((size_t)j << 7) + (c - 128)];
        m = fmaxf(m, fabsf(val));
    }
    atomicMax(&cm[tx], __float_as_uint(m));
    __syncthreads();
    if (threadIdx.x < 64)
        atomicMax((uint_t*)&cmax[c0 + threadIdx.x], cm[threadIdx.x]);
}

// ---------------------------------------------------------------------------
// K2: build Bi8 with per-column scale 127/cmax[c]; dq[c] = cmax[c]/127^2.
template<int REP>
__global__ __launch_bounds__(256) void preQ(const float* __restrict__ u,
    const float* __restrict__ v, const float* __restrict__ s, const float* __restrict__ rinv,
    const float* __restrict__ cmax, char* __restrict__ Bi8, float* __restrict__ dq)
{
    const int j0 = (blockIdx.x & 127) << 6;
    const int c0 = (blockIdx.x >> 7) << 6;
    __shared__ float tile[64][65];
    for (int rep = 0; rep < REP; ++rep) {
        const int tx = threadIdx.x & 63;
        const int ty = threadIdx.x >> 6;
        #pragma unroll
        for (int rr = 0; rr < 16; ++rr) {
            const int jl = ty + (rr << 2);
            const int j = j0 + jl;
            const int c = c0 + tx;
            tile[jl][tx] = (c < 128) ? s[j] * u[((size_t)j << 7) + c]
                                     : rinv[j] * v[((size_t)j << 7) + (c - 128)];
        }
        __syncthreads();
        const int cl = threadIdx.x & 63;
        const int jq = threadIdx.x >> 6;
        const float cmv = cmax[c0 + cl];
        const float rs = cmv > 0.f ? 127.f / cmv : 0.f;
        uint_t w4[4];
        #pragma unroll
        for (int g = 0; g < 4; ++g) {
            uint_t wv = 0;
            #pragma unroll
            for (int b = 0; b < 4; ++b) {
                int q = __float2int_rn(tile[(jq << 4) + (g << 2) + b][cl] * rs);
                q = q > 127 ? 127 : (q < -127 ? -127 : q);
                wv |= ((uint_t)(q & 0xff)) << (8 * b);
            }
            w4[g] = wv;
        }
        uint4 st; st.x = w4[0]; st.y = w4[1]; st.z = w4[2]; st.w = w4[3];
        *(uint4*)(Bi8 + ((size_t)(c0 + cl) << 13) + j0 + (jq << 4)) = st;
        if ((blockIdx.x & 127) == 0 && threadIdx.x < 64)
            dq[c0 + threadIdx.x] = cmax[c0 + threadIdx.x] * (1.f / 16129.f);
        __syncthreads();
    }
}

// ---------------------------------------------------------------------------
// K3a: ring-4 i8 GEMM (R10-proven). BM=BN=256, BK=64B, 8 waves 2Mx4N,
// 4-deep 32KB slots. REP: acc reset per rep -> idempotent.
#define WAITB(S) do {                                         \
    asm volatile("s_waitcnt " S ::: "memory");                \
    __builtin_amdgcn_sched_barrier(0);                        \
    __builtin_amdgcn_s_barrier();                             \
    __builtin_amdgcn_sched_barrier(0);                        \
} while (0)

template<int REP>
__global__ __launch_bounds__(512, 2) void gemm_i8(const char* __restrict__ A,
    const char* __restrict__ Bt, ushort_t* __restrict__ Yb)
{
    __shared__ char lds[4 * 32768];       // ring: [4][A 16KB | B 16KB]
    const int bid = blockIdx.x;
    const int mb = bid & 31;
    const int ks = bid >> 5;
    const size_t mBase = (size_t)mb * 256;
    const int tid = threadIdx.x;
    const int w = tid >> 6, l = tid & 63;
    const int wr = w >> 2, wc = w & 3;
    const int frow = l & 15, fk = l >> 4;
    const int fsl = ((fk ^ ((frow >> 1) & 3)) << 4);
    const int srow = l >> 2;
    const int skoff = (((l & 3) ^ ((l >> 3) & 3)) << 4);
    const int kBeg = ks << 10;

    i32x4 acc[8][4];

    auto STAGE = [&](int t) {
        const int k0 = kBeg + (t << 6);
        char* base = &lds[(t & 3) << 15];
        #pragma unroll
        for (int q = 0; q < 2; ++q) {
            const int c = (w << 1) + q;
            const int row = (c << 4) + srow;
            __builtin_amdgcn_global_load_lds(
                (const gbl_void_t*)(A + ((mBase + row) << 13) + k0 + skoff),
                (lds_void_t*)(base + (c << 10)), 16, 0, 0);
            __builtin_amdgcn_global_load_lds(
                (const gbl_void_t*)(Bt + ((size_t)row << 13) + k0 + skoff),
                (lds_void_t*)(base + 16384 + (c << 10)), 16, 0, 0);
        }
    };
    auto COMPUTE = [&](int T) {
        const char* buf = &lds[(T & 3) << 15];
        i32x4 av[8], bv[4];
        #pragma unroll
        for (int mi = 0; mi < 8; ++mi) {
            const int row = (wr << 7) + (mi << 4) + frow;
            av[mi] = *(const i32x4*)(buf + (row << 6) + fsl);
        }
        #pragma unroll
        for (int ni = 0; ni < 4; ++ni) {
            const int col = (wc << 6) + (ni << 4) + frow;
            bv[ni] = *(const i32x4*)(buf + 16384 + (col << 6) + fsl);
        }
        __builtin_amdgcn_s_setprio(1);
        #pragma unroll
        for (int mi = 0; mi < 8; ++mi)
            #pragma unroll
            for (int ni = 0; ni < 4; ++ni)
                acc[mi][ni] = __builtin_amdgcn_mfma_i32_16x16x64_i8(
                    av[mi], bv[ni], acc[mi][ni], 0, 0, 0);
        __builtin_amdgcn_s_setprio(0);
    };

    for (int rep = 0; rep < REP; ++rep) {
        #pragma unroll
        for (int mi = 0; mi < 8; ++mi)
            #pragma unroll
            for (int ni = 0; ni < 4; ++ni)
                acc[mi][ni] = (i32x4){0, 0, 0, 0};
        STAGE(0); STAGE(1); STAGE(2);
        #pragma unroll 1
        for (int T = 0; T < NTQ - 3; ++T) {
            WAITB("vmcnt(8)");
            STAGE(T + 3);
            COMPUTE(T);
        }
        WAITB("vmcnt(8)"); COMPUTE(NTQ - 3);
        WAITB("vmcnt(4)"); COMPUTE(NTQ - 2);
        WAITB("vmcnt(0)"); COMPUTE(NTQ - 1);
    }
    __syncthreads();

    // Epilogue: i32 -> f32 -> bf16 Cs[256][256] -> coalesced stores.
    ushort_t* Cs = (ushort_t*)lds;
    const int orow = (l >> 4) << 2;
    const int ocol = l & 15;
    #pragma unroll
    for (int mi = 0; mi < 8; ++mi) {
        #pragma unroll
        for (int ni = 0; ni < 4; ++ni) {
            const int rl = (wr << 7) + (mi << 4) + orow;
            const int cl = (wc << 6) + (ni << 4) + ocol;
            #pragma unroll
            for (int r = 0; r < 4; ++r)
                Cs[(rl + r) * 256 + cl] = f2bf((float)acc[mi][ni][r]);
        }
    }
    __syncthreads();
    const size_t sliceBase = ((size_t)ks * NN + mBase) * 256;
    #pragma unroll
    for (int p = 0; p < 16; ++p) {
        const int idx16 = (p << 9) + tid;
        const int row   = idx16 >> 5;
        const int c16   = idx16 & 31;
        const uint4 v = *(const uint4*)(&Cs[(row << 8) + (c16 << 3)]);
        *(uint4*)(Yb + sliceBase + (size_t)row * 256 + (c16 << 3)) = v;
    }
}

// ---------------------------------------------------------------------------
// K3b (L4): half-width i8 GEMM. BM=256 BN=128, 4 waves, ring-2 (48KB).
__global__ __launch_bounds__(256, 2) void gemm_half_i8(const char* __restrict__ A,
    const char* __restrict__ Bt, ushort_t* __restrict__ Yb, int nbOff, int nbCount)
{
    __shared__ char lds[2 * 24576];       // per buf: A 16KB | B 8KB
    const int bid  = blockIdx.x;
    const int mb   = bid & 31;
    const int rest = bid >> 5;
    const int nb   = nbOff + (rest % nbCount);
    const int ks   = rest / nbCount;
    const size_t mBase = (size_t)mb * 256;
    const size_t nBase = (size_t)nb * 128;
    const int tid = threadIdx.x;
    const int w = tid >> 6, l = tid & 63;
    const int wr = w >> 1, wc = w & 1;
    const int frow = l & 15, fk = l >> 4;
    const int fsl = ((fk ^ ((frow >> 1) & 3)) << 4);
    const int srow = l >> 2;
    const int skoff = (((l & 3) ^ ((l >> 3) & 3)) << 4);
    const int kBeg = ks << 10;

    i32x4 acc[8][4] = {};

    auto STAGE = [&](int t) {
        const int k0 = kBeg + (t << 6);
        char* base = &lds[(t & 1) * 24576];
        #pragma unroll
        for (int q = 0; q < 4; ++q) {
            const int c = (w << 2) + q;
            const int row = (c << 4) + srow;
            __builtin_amdgcn_global_load_lds(
                (const gbl_void_t*)(A + ((mBase + row) << 13) + k0 + skoff),
                (lds_void_t*)(base + (c << 10)), 16, 0, 0);
        }
        #pragma unroll
        for (int q = 0; q < 2; ++q) {
            const int c = (w << 1) + q;
            const int row = (c << 4) + srow;
            __builtin_amdgcn_global_load_lds(
                (const gbl_void_t*)(Bt + ((nBase + row) << 13) + k0 + skoff),
                (lds_void_t*)(base + 16384 + (c << 10)), 16, 0, 0);
        }
    };

    STAGE(0);
    __syncthreads();
    #pragma unroll 1
    for (int T = 0; T < NTQ; ++T) {
        if (T + 1 < NTQ) STAGE(T + 1);
        const char* buf = &lds[(T & 1) * 24576];
        i32x4 av[8], bv[4];
        #pragma unroll
        for (int mi = 0; mi < 8; ++mi) {
            const int row = (wr << 7) + (mi << 4) + frow;
            av[mi] = *(const i32x4*)(buf + (row << 6) + fsl);
        }
        #pragma unroll
        for (int ni = 0; ni < 4; ++ni) {
            const int col = (wc << 6) + (ni << 4) + frow;
            bv[ni] = *(const i32x4*)(buf + 16384 + (col << 6) + fsl);
        }
        __builtin_amdgcn_s_setprio(1);
        #pragma unroll
        for (int mi = 0; mi < 8; ++mi)
            #pragma unroll
            for (int ni = 0; ni < 4; ++ni)
                acc[mi][ni] = __builtin_amdgcn_mfma_i32_16x16x64_i8(
                    av[mi], bv[ni], acc[mi][ni], 0, 0, 0);
        __builtin_amdgcn_s_setprio(0);
        __syncthreads();
    }

    const int orow = (l >> 4) << 2;
    const int ocol = l & 15;
    const size_t sliceBase = ((size_t)ks * NN + mBase) * 256 + nBase;
    #pragma unroll
    for (int p = 0; p < 2; ++p) {
        __syncthreads();
        ushort_t* Cs = (ushort_t*)lds;     // [128][128] bf16
        #pragma unroll
        for (int mi = 0; mi < 4; ++mi) {
            #pragma unroll
            for (int ni = 0; ni < 4; ++ni) {
                const int rl = (wr << 6) + (mi << 4) + orow;
                const int cl = (wc << 6) + (ni << 4) + ocol;
                #pragma unroll
                for (int r = 0; r < 4; ++r)
                    Cs[(rl + r) * 128 + cl] = f2bf((float)acc[(p << 2) + mi][ni][r]);
            }
        }
        __syncthreads();
        #pragma unroll
        for (int pp = 0; pp < 8; ++pp) {
            const int idx16 = (pp << 8) + tid;
            const int lrow  = idx16 >> 4;
            const int c16   = idx16 & 15;
            const int rowIn = ((lrow >> 6) << 7) + (p << 6) + (lrow & 63);
            const uint4 v = *(const uint4*)(&Cs[(lrow << 7) + (c16 << 3)]);
            *(uint4*)(Yb + sliceBase + (size_t)rowIn * 256 + (c16 << 3)) = v;
        }
    }
}

// ---------------------------------------------------------------------------
// K4: reduce KS bf16 partials, dequant by dq[c], postscale; track next-level
// per-column max into cmaxN. REP: idempotent.
template<int REP>
__global__ __launch_bounds__(256) void reduce_post(const ushort_t* __restrict__ Yb,
    const float* __restrict__ u, const float* __restrict__ v,
    const float* __restrict__ s, const float* __restrict__ rinv,
    float* __restrict__ hop_out, float* __restrict__ walk_out,
    const float* __restrict__ dq, float* __restrict__ cmaxN, int c0Off)
{
    const int j0 = (blockIdx.x & 127) << 6;
    const int c0 = ((blockIdx.x >> 7) + c0Off) << 6;
    const bool hop = (c0 < 128);
    if (hop && hop_out == nullptr) return;
    __shared__ uint_t cm[64];
    for (int rep = 0; rep < REP; ++rep) {
        if (cmaxN && threadIdx.x < 64) cm[threadIdx.x] = 0;
        if (cmaxN) __syncthreads();
        const int cg = threadIdx.x & 15;
        const int jr = threadIdx.x >> 4;
        const size_t SL = (size_t)NN * 256;
        const float4 dqv = ((const float4*)dq)[(c0 >> 2) + cg];
        float lm0 = 0.f, lm1 = 0.f, lm2 = 0.f, lm3 = 0.f;
        #pragma unroll
        for (int it = 0; it < 4; ++it) {
            const int jl = jr + (it << 4);
            const int j  = j0 + jl;
            const int c  = c0 + (cg << 2);
            const ushort_t* p = Yb + ((size_t)j << 8) + c;
            float e0 = 0.f, e1 = 0.f, e2 = 0.f, e3 = 0.f;
            #pragma unroll
            for (int kss = 0; kss < KS; ++kss) {
                const uint2 q = *(const uint2*)(p + kss * SL);
                e0 += bf2f(q.x & 0xffffu);
                e1 += __uint_as_float(q.x & 0xffff0000u);
                e2 += bf2f(q.y & 0xffffu);
                e3 += __uint_as_float(q.y & 0xffff0000u);
            }
            e0 *= dqv.x; e1 *= dqv.y; e2 *= dqv.z; e3 *= dqv.w;
            float4 o; float scale;
            if (hop) {
                const float si = s[j], si2 = si * si;
                const float4 uu = ((const float4*)u)[((size_t)j << 5) + (c >> 2)];
                o.x = si * e0 + si2 * uu.x;  o.y = si * e1 + si2 * uu.y;
                o.z = si * e2 + si2 * uu.z;  o.w = si * e3 + si2 * uu.w;
                ((float4*)hop_out)[((size_t)j << 5) + (c >> 2)] = o;
                scale = si;
            } else {
                const int cw = c - 128;
                const float4 vv = ((const float4*)v)[((size_t)j << 5) + (cw >> 2)];
                o.x = 0.5f * (vv.x + e0);  o.y = 0.5f * (vv.y + e1);
                o.z = 0.5f * (vv.z + e2);  o.w = 0.5f * (vv.w + e3);
                ((float4*)walk_out)[((size_t)j << 5) + (cw >> 2)] = o;
                scale = rinv[j];
            }
            if (cmaxN) {
                lm0 = fmaxf(lm0, fabsf(scale * o.x));
                lm1 = fmaxf(lm1, fabsf(scale * o.y));
                lm2 = fmaxf(lm2, fabsf(scale * o.z));
                lm3 = fmaxf(lm3, fabsf(scale * o.w));
            }
        }
        if (cmaxN) {
            atomicMax(&cm[(cg << 2) + 0], __float_as_uint(lm0));
            atomicMax(&cm[(cg << 2) + 1], __float_as_uint(lm1));
            atomicMax(&cm[(cg << 2) + 2], __float_as_uint(lm2));
            atomicMax(&cm[(cg << 2) + 3], __float_as_uint(lm3));
            __syncthreads();
            if (threadIdx.x < 64)
                atomicMax((uint_t*)&cmaxN[c0 + threadIdx.x], cm[threadIdx.x]);
            __syncthreads();
        }
    }
}

// ---------------------------------------------------------------------------
// K5: 6-way attention fusion (unchanged).
__global__ __launch_bounds__(256) void fuse_attn(const float* __restrict__ X,
    const float* __restrict__ hA, const float* __restrict__ hA2, const float* __restrict__ hA3,
    const float* __restrict__ px, const float* __restrict__ p2x, const float* __restrict__ p4x,
    const float* __restrict__ a, float* __restrict__ hp)
{
    const int w = threadIdx.x >> 6, l = threadIdx.x & 63;
    const size_t i = (size_t)blockIdx.x * 4 + w;
    const size_t base = i << 7;
    float f[6][2];
    float e[6] = {0.f, 0.f, 0.f, 0.f, 0.f, 0.f};
    #pragma unroll
    for (int h = 0; h < 2; ++h) {
        const int k = l + (h << 6);
        const float a2 = a[128 + k];
        const float x   = X[base + k];
        const float t1  = leaky(hA [base + k]);
        const float t2  = leaky(hA2[base + k]);
        const float t3  = leaky(hA3[base + k]);
        const float pk  = px [base + k];
        const float p2k = p2x[base + k];
        const float p4k = p4x[base + k];
        const float s1 = fabsf(x - pk);
        const float s2 = fabsf(pk - p2k);
        const float s3 = fabsf(p2k - p4k);
        f[0][h] = t1; f[1][h] = t2; f[2][h] = t3;
        f[3][h] = s1; f[4][h] = s2; f[5][h] = s3;
        e[0] += fmaxf(t1, 0.f) * a2;
        e[1] += fmaxf(t2, 0.f) * a2;
        e[2] += fmaxf(t3, 0.f) * a2;
        e[3] += s1 * a2;
        e[4] += s2 * a2;
        e[5] += s3 * a2;
    }
    #pragma unroll
    for (int ss = 0; ss < 6; ++ss) {
        #pragma unroll
        for (int off = 32; off; off >>= 1) e[ss] += __shfl_xor(e[ss], off);
    }
    float mx = e[0];
    #pragma unroll
    for (int ss = 1; ss < 6; ++ss) mx = fmaxf(mx, e[ss]);
    float at[6], sum = 0.f;
    #pragma unroll
    for (int ss = 0; ss < 6; ++ss) { at[ss] = expf(e[ss] - mx); sum += at[ss]; }
    const float inv = 1.f / (6.f * sum);
    #pragma unroll
    for (int h = 0; h < 2; ++h) {
        float o = 0.f;
        #pragma unroll
        for (int ss = 0; ss < 6; ++ss) o += at[ss] * f[ss][h];
        hp[base + l + (h << 6)] = o * inv;
    }
}

// ---------------------------------------------------------------------------
// K6: out = leaky(Hm @ W^T + b), f32.
__global__ __launch_bounds__(256) void mlp(const float* __restrict__ Hm,
    const float* __restrict__ W, const float* __restrict__ b, float* __restrict__ out)
{
    __shared__ float Ws[128 * 140];
    __shared__ float Hs[16 * 140];
    const int node0 = blockIdx.x << 4;
    for (int rr = 0; rr < 64; ++rr) {
        const int idx = rr * 256 + threadIdx.x;
        Ws[(idx >> 7) * 140 + (idx & 127)] = W[idx];
    }
    #pragma unroll
    for (int rr = 0; rr < 8; ++rr) {
        const int idx = rr * 256 + threadIdx.x;
        Hs[(idx >> 7) * 140 + (idx & 127)] = Hm[((size_t)node0 << 7) + idx];
    }
    __syncthreads();
    const int c = threadIdx.x & 15;
    const int n = threadIdx.x >> 4;
    float acc[8] = {};
    for (int k4 = 0; k4 < 32; ++k4) {
        const float4 h4 = *(const float4*)(&Hs[n * 140 + (k4 << 2)]);
        #pragma unroll
        for (int r = 0; r < 8; ++r) {
            const float4 w4 = *(const float4*)(&Ws[(c + (r << 4)) * 140 + (k4 << 2)]);
            acc[r] += h4.x * w4.x + h4.y * w4.y + h4.z * w4.z + h4.w * w4.w;
        }
    }
    const size_t obase = ((size_t)(node0 + n)) << 7;
    #pragma unroll
    for (int r = 0; r < 8; ++r) {
        const int o = c + (r << 4);
        out[obase + o] = leaky(acc[r] + b[o]);
    }
}

// ---------------------------------------------------------------------------
extern "C" void kernel_launch(void* const* d_in, const int* in_sizes, int n_in,
                              void* d_out, int out_size, void* d_ws, size_t ws_size,
                              hipStream_t stream)
{
    const float* X   = (const float*)d_in[0];
    const float* adj = (const float*)d_in[1];
    const float* W1  = (const float*)d_in[2];
    const float* b1  = (const float*)d_in[3];
    const float* W2  = (const float*)d_in[4];
    const float* b2  = (const float*)d_in[5];
    const float* a   = (const float*)d_in[6];
    float* out = (float*)d_out;

    // Workspace layout (~132.2 MB)
    char* ws = (char*)d_ws;
    char*     adjq = ws;                                   //  64 MB i8 adj
    char*     Bi8  = ws + 67108864ull;                     //   2 MB i8 B
    ushort_t* Yb   = (ushort_t*)(ws + 69206016ull);        //  32 MB bf16 partials
    float* hA  = (float*)(ws + 102760448ull);              //   4 MB each below
    float* hA2 = hA  + 1048576;
    float* hA3 = hA2 + 1048576;
    float* px  = hA3 + 1048576;
    float* p2x = px  + 1048576;
    float* p3x = p2x + 1048576;
    float* p4x = p3x + 1048576;
    float* sbuf  = p4x + 1048576;                          // 32 KB
    float* rinvb = sbuf + 8192;                            // 32 KB
    float* cmaxb = rinvb + 8192;                           // 4 x 256 f32
    float* dq    = cmaxb + 1024;                           // 256 f32
    float* cmax1 = cmaxb, *cmax2 = cmaxb + 256, *cmax3 = cmaxb + 512, *cmax4 = cmaxb + 768;
    float* hp   = (float*)Yb;                 // overlay: Yb dead after L4 reduce
    float* out1 = (float*)(ws + 69206016ull + 4194304ull);

    // DIAGNOSTIC ROUND: REP-inflated instances (idempotent — outputs identical)
    // surface per-kernel dur/counters above the ~155us harness fills.
    conv_rowsum<4><<<8192, 256, 0, stream>>>(adj, adjq, sbuf, rinvb, cmaxb);

    // Level 1 (diag instances)
    preMax<<<512, 256, 0, stream>>>(X, X, sbuf, rinvb, cmax1);
    preQ<40>  <<<512, 256, 0, stream>>>(X, X, sbuf, rinvb, cmax1, Bi8, dq);
    gemm_i8<12><<<256, 512, 0, stream>>>(adjq, Bi8, Yb);
    reduce_post<24><<<512, 256, 0, stream>>>(Yb, X, X, sbuf, rinvb,
                                             hA, px, dq, cmax2, 0);
    // Level 2
    preQ<1>   <<<512, 256, 0, stream>>>(hA, px, sbuf, rinvb, cmax2, Bi8, dq);
    gemm_i8<1><<<256, 512, 0, stream>>>(adjq, Bi8, Yb);
    reduce_post<1><<<512, 256, 0, stream>>>(Yb, hA, px, sbuf, rinvb,
                                            hA2, p2x, dq, cmax3, 0);
    // Level 3
    preQ<1>   <<<512, 256, 0, stream>>>(hA2, p2x, sbuf, rinvb, cmax3, Bi8, dq);
    gemm_i8<1><<<256, 512, 0, stream>>>(adjq, Bi8, Yb);
    reduce_post<1><<<512, 256, 0, stream>>>(Yb, hA2, p2x, sbuf, rinvb,
                                            hA3, p3x, dq, cmax4, 0);
    // Level 4 (walk half only)
    preQ<1>   <<<512, 256, 0, stream>>>(hA3, p3x, sbuf, rinvb, cmax4, Bi8, dq);
    gemm_half_i8<<<256, 256, 0, stream>>>(adjq, Bi8, Yb, 1, 1);
    reduce_post<1><<<256, 256, 0, stream>>>(Yb, nullptr, p3x, sbuf, rinvb,
                                            nullptr, p4x, dq, nullptr, 2);

    fuse_attn<<<2048, 256, 0, stream>>>(X, hA, hA2, hA3, px, p2x, p4x, a, hp);
    mlp<<<512, 256, 0, stream>>>(hp, W1, b1, out1);
    mlp<<<512, 256, 0, stream>>>(out1, W2, b2, out);
}

// Round 12
// 460.376 us; speedup vs baseline: 1.5275x; 1.5275x over previous
//
#include <hip/hip_runtime.h>

typedef unsigned short ushort_t;
typedef unsigned int   uint_t;
typedef int   i32x4 __attribute__((ext_vector_type(4)));

typedef __attribute__((address_space(3))) void lds_void_t;
typedef __attribute__((address_space(1))) void gbl_void_t;

#define NN 8192
#define HH 128
#define KS 8          // K-split factor
#define KLEN 1024     // K elements per split slice
#define NTQ 16        // K-tiles per block (KLEN / 64, i8 BK=64)
#define NBAR 512u     // blocks in the in-kernel device barrier

__device__ __forceinline__ ushort_t f2bf(float x) {
    uint_t u = __float_as_uint(x);
    u += 0x7fffu + ((u >> 16) & 1u);          // RNE
    return (ushort_t)(u >> 16);
}
__device__ __forceinline__ float bf2f(uint_t lo16) { return __uint_as_float(lo16 << 16); }
__device__ __forceinline__ float leaky(float x) { return x > 0.f ? x : 0.01f * x; }

// Device-scope arrive-and-wait barrier (all NBAR blocks co-resident: 2/CU at
// ~17KB LDS / 256 thr, 8x headroom). Counter zeroed by conv each call; re-runs
// are idempotent (counter only grows past NBAR -> spin exits immediately).
__device__ __forceinline__ void grid_barrier(uint_t* ctr) {
    __threadfence();
    __syncthreads();
    if (threadIdx.x == 0) {
        __hip_atomic_fetch_add(ctr, 1u, __ATOMIC_ACQ_REL, __HIP_MEMORY_SCOPE_AGENT);
        while (__hip_atomic_load(ctr, __ATOMIC_ACQUIRE, __HIP_MEMORY_SCOPE_AGENT) < NBAR)
            __builtin_amdgcn_s_sleep(2);
    }
    __syncthreads();
}
__device__ __forceinline__ float cmax_read(const float* p) {
    return __uint_as_float(__hip_atomic_load((const uint_t*)p,
        __ATOMIC_RELAXED, __HIP_MEMORY_SCOPE_AGENT));
}

// ---------------------------------------------------------------------------
// K0: adj f32 -> i8 + row sums. Block 0 zeroes cmax/dq/counter region.
__global__ __launch_bounds__(256) void conv_rowsum(const float* __restrict__ adj,
    char* __restrict__ adjq, float* __restrict__ s, float* __restrict__ rinv,
    float* __restrict__ zbase)
{
    const int i = blockIdx.x;
    if (i == 0) {
        const float4 z{0.f, 0.f, 0.f, 0.f};
        ((float4*)zbase)[threadIdx.x] = z;                     // 1024 floats
        if (threadIdx.x < 128) ((float4*)zbase)[256 + threadIdx.x] = z;  // +512
    }
    const float4* arow = (const float4*)(adj + ((size_t)i << 13));
    uint_t* brow = (uint_t*)(adjq + ((size_t)i << 13));
    float partial = 0.f;
    for (int t = threadIdx.x; t < 2048; t += 256) {
        const float4 v = arow[t];
        partial += (v.x + v.y) + (v.z + v.w);
        const uint_t q0 = (uint_t)__float2int_rn(v.x * 127.f);
        const uint_t q1 = (uint_t)__float2int_rn(v.y * 127.f);
        const uint_t q2 = (uint_t)__float2int_rn(v.z * 127.f);
        const uint_t q3 = (uint_t)__float2int_rn(v.w * 127.f);
        brow[t] = q0 | (q1 << 8) | (q2 << 16) | (q3 << 24);
    }
    #pragma unroll
    for (int off = 32; off; off >>= 1) partial += __shfl_xor(partial, off);
    __shared__ float ps[4];
    if ((threadIdx.x & 63) == 0) ps[threadIdx.x >> 6] = partial;
    __syncthreads();
    if (threadIdx.x == 0) {
        const float tot = (ps[0] + ps[1]) + (ps[2] + ps[3]);
        s[i]    = rsqrtf(tot + 1.0f);
        rinv[i] = 1.0f / tot;
    }
}

// ---------------------------------------------------------------------------
// K1: level-1 B build: colmax (phase 1) -> device barrier -> quantize (phase 2).
// Replaces preMax+preQ; tile kept in LDS across the barrier (no global re-read).
__global__ __launch_bounds__(256) void quantX(const float* __restrict__ X,
    const float* __restrict__ s, const float* __restrict__ rinv,
    float* __restrict__ cmax, char* __restrict__ Bi8, float* __restrict__ dq,
    uint_t* __restrict__ ctr)
{
    const int j0 = (blockIdx.x & 127) << 6;
    const int c0 = (blockIdx.x >> 7) << 6;
    __shared__ float tile[64][65];
    __shared__ uint_t cm[64];
    const int tid = threadIdx.x;
    if (tid < 64) cm[tid] = 0;
    __syncthreads();
    const int tx = tid & 63, ty = tid >> 6;
    float m = 0.f;
    #pragma unroll
    for (int rr = 0; rr < 16; ++rr) {
        const int jl = ty + (rr << 2);
        const int j = j0 + jl;
        const int c = c0 + tx;
        const float val = (c < 128) ? s[j] * X[((size_t)j << 7) + c]
                                    : rinv[j] * X[((size_t)j << 7) + (c - 128)];
        tile[jl][tx] = val;
        m = fmaxf(m, fabsf(val));
    }
    atomicMax(&cm[tx], __float_as_uint(m));
    __syncthreads();
    if (tid < 64) atomicMax((uint_t*)&cmax[c0 + tid], cm[tid]);
    grid_barrier(ctr);
    const int cl = tid & 63, jq = tid >> 6;
    const float cmv = cmax_read(&cmax[c0 + cl]);
    const float rs = cmv > 0.f ? 127.f / cmv : 0.f;
    uint_t w4[4];
    #pragma unroll
    for (int g = 0; g < 4; ++g) {
        uint_t wv = 0;
        #pragma unroll
        for (int b = 0; b < 4; ++b) {
            int q = __float2int_rn(tile[(jq << 4) + (g << 2) + b][cl] * rs);
            q = q > 127 ? 127 : (q < -127 ? -127 : q);
            wv |= ((uint_t)(q & 0xff)) << (8 * b);
        }
        w4[g] = wv;
    }
    uint4 st; st.x = w4[0]; st.y = w4[1]; st.z = w4[2]; st.w = w4[3];
    *(uint4*)(Bi8 + ((size_t)(c0 + cl) << 13) + j0 + (jq << 4)) = st;
    if ((blockIdx.x & 127) == 0 && tid < 64)
        dq[c0 + tid] = cmv * (1.f / 16129.f);
}

// ---------------------------------------------------------------------------
// K3a: ring-4 i8 GEMM (R10-proven). BM=BN=256, BK=64B, 8 waves 2Mx4N,
// 4-deep 32KB slots, 128 KiB LDS.
#define WAITB(S) do {                                         \
    asm volatile("s_waitcnt " S ::: "memory");                \
    __builtin_amdgcn_sched_barrier(0);                        \
    __builtin_amdgcn_s_barrier();                             \
    __builtin_amdgcn_sched_barrier(0);                        \
} while (0)

__global__ __launch_bounds__(512, 2) void gemm_i8(const char* __restrict__ A,
    const char* __restrict__ Bt, ushort_t* __restrict__ Yb)
{
    __shared__ char lds[4 * 32768];       // ring: [4][A 16KB | B 16KB]
    const int bid = blockIdx.x;
    const int mb = bid & 31;
    const int ks = bid >> 5;
    const size_t mBase = (size_t)mb * 256;
    const int tid = threadIdx.x;
    const int w = tid >> 6, l = tid & 63;
    const int wr = w >> 2, wc = w & 3;
    const int frow = l & 15, fk = l >> 4;
    const int fsl = ((fk ^ ((frow >> 1) & 3)) << 4);
    const int srow = l >> 2;
    const int skoff = (((l & 3) ^ ((l >> 3) & 3)) << 4);
    const int kBeg = ks << 10;

    i32x4 acc[8][4] = {};

    auto STAGE = [&](int t) {
        const int k0 = kBeg + (t << 6);
        char* base = &lds[(t & 3) << 15];
        #pragma unroll
        for (int q = 0; q < 2; ++q) {
            const int c = (w << 1) + q;
            const int row = (c << 4) + srow;
            __builtin_amdgcn_global_load_lds(
                (const gbl_void_t*)(A + ((mBase + row) << 13) + k0 + skoff),
                (lds_void_t*)(base + (c << 10)), 16, 0, 0);
            __builtin_amdgcn_global_load_lds(
                (const gbl_void_t*)(Bt + ((size_t)row << 13) + k0 + skoff),
                (lds_void_t*)(base + 16384 + (c << 10)), 16, 0, 0);
        }
    };
    auto COMPUTE = [&](int T) {
        const char* buf = &lds[(T & 3) << 15];
        i32x4 av[8], bv[4];
        #pragma unroll
        for (int mi = 0; mi < 8; ++mi) {
            const int row = (wr << 7) + (mi << 4) + frow;
            av[mi] = *(const i32x4*)(buf + (row << 6) + fsl);
        }
        #pragma unroll
        for (int ni = 0; ni < 4; ++ni) {
            const int col = (wc << 6) + (ni << 4) + frow;
            bv[ni] = *(const i32x4*)(buf + 16384 + (col << 6) + fsl);
        }
        __builtin_amdgcn_s_setprio(1);
        #pragma unroll
        for (int mi = 0; mi < 8; ++mi)
            #pragma unroll
            for (int ni = 0; ni < 4; ++ni)
                acc[mi][ni] = __builtin_amdgcn_mfma_i32_16x16x64_i8(
                    av[mi], bv[ni], acc[mi][ni], 0, 0, 0);
        __builtin_amdgcn_s_setprio(0);
    };

    STAGE(0); STAGE(1); STAGE(2);
    #pragma unroll 1
    for (int T = 0; T < NTQ - 3; ++T) {
        WAITB("vmcnt(8)");
        STAGE(T + 3);
        COMPUTE(T);
    }
    WAITB("vmcnt(8)"); COMPUTE(NTQ - 3);
    WAITB("vmcnt(4)"); COMPUTE(NTQ - 2);
    WAITB("vmcnt(0)"); COMPUTE(NTQ - 1);
    __syncthreads();

    ushort_t* Cs = (ushort_t*)lds;
    const int orow = (l >> 4) << 2;
    const int ocol = l & 15;
    #pragma unroll
    for (int mi = 0; mi < 8; ++mi) {
        #pragma unroll
        for (int ni = 0; ni < 4; ++ni) {
            const int rl = (wr << 7) + (mi << 4) + orow;
            const int cl = (wc << 6) + (ni << 4) + ocol;
            #pragma unroll
            for (int r = 0; r < 4; ++r)
                Cs[(rl + r) * 256 + cl] = f2bf((float)acc[mi][ni][r]);
        }
    }
    __syncthreads();
    const size_t sliceBase = ((size_t)ks * NN + mBase) * 256;
    #pragma unroll
    for (int p = 0; p < 16; ++p) {
        const int idx16 = (p << 9) + tid;
        const int row   = idx16 >> 5;
        const int c16   = idx16 & 31;
        const uint4 v = *(const uint4*)(&Cs[(row << 8) + (c16 << 3)]);
        *(uint4*)(Yb + sliceBase + (size_t)row * 256 + (c16 << 3)) = v;
    }
}

// ---------------------------------------------------------------------------
// K3b (L4): half-width i8 GEMM. BM=256 BN=128, 4 waves, ring-2 (48KB).
__global__ __launch_bounds__(256, 2) void gemm_half_i8(const char* __restrict__ A,
    const char* __restrict__ Bt, ushort_t* __restrict__ Yb, int nbOff, int nbCount)
{
    __shared__ char lds[2 * 24576];       // per buf: A 16KB | B 8KB
    const int bid  = blockIdx.x;
    const int mb   = bid & 31;
    const int rest = bid >> 5;
    const int nb   = nbOff + (rest % nbCount);
    const int ks   = rest / nbCount;
    const size_t mBase = (size_t)mb * 256;
    const size_t nBase = (size_t)nb * 128;
    const int tid = threadIdx.x;
    const int w = tid >> 6, l = tid & 63;
    const int wr = w >> 1, wc = w & 1;
    const int frow = l & 15, fk = l >> 4;
    const int fsl = ((fk ^ ((frow >> 1) & 3)) << 4);
    const int srow = l >> 2;
    const int skoff = (((l & 3) ^ ((l >> 3) & 3)) << 4);
    const int kBeg = ks << 10;

    i32x4 acc[8][4] = {};

    auto STAGE = [&](int t) {
        const int k0 = kBeg + (t << 6);
        char* base = &lds[(t & 1) * 24576];
        #pragma unroll
        for (int q = 0; q < 4; ++q) {
            const int c = (w << 2) + q;
            const int row = (c << 4) + srow;
            __builtin_amdgcn_global_load_lds(
                (const gbl_void_t*)(A + ((mBase + row) << 13) + k0 + skoff),
                (lds_void_t*)(base + (c << 10)), 16, 0, 0);
        }
        #pragma unroll
        for (int q = 0; q < 2; ++q) {
            const int c = (w << 1) + q;
            const int row = (c << 4) + srow;
            __builtin_amdgcn_global_load_lds(
                (const gbl_void_t*)(Bt + ((nBase + row) << 13) + k0 + skoff),
                (lds_void_t*)(base + 16384 + (c << 10)), 16, 0, 0);
        }
    };

    STAGE(0);
    __syncthreads();
    #pragma unroll 1
    for (int T = 0; T < NTQ; ++T) {
        if (T + 1 < NTQ) STAGE(T + 1);
        const char* buf = &lds[(T & 1) * 24576];
        i32x4 av[8], bv[4];
        #pragma unroll
        for (int mi = 0; mi < 8; ++mi) {
            const int row = (wr << 7) + (mi << 4) + frow;
            av[mi] = *(const i32x4*)(buf + (row << 6) + fsl);
        }
        #pragma unroll
        for (int ni = 0; ni < 4; ++ni) {
            const int col = (wc << 6) + (ni << 4) + frow;
            bv[ni] = *(const i32x4*)(buf + 16384 + (col << 6) + fsl);
        }
        __builtin_amdgcn_s_setprio(1);
        #pragma unroll
        for (int mi = 0; mi < 8; ++mi)
            #pragma unroll
            for (int ni = 0; ni < 4; ++ni)
                acc[mi][ni] = __builtin_amdgcn_mfma_i32_16x16x64_i8(
                    av[mi], bv[ni], acc[mi][ni], 0, 0, 0);
        __builtin_amdgcn_s_setprio(0);
        __syncthreads();
    }

    const int orow = (l >> 4) << 2;
    const int ocol = l & 15;
    const size_t sliceBase = ((size_t)ks * NN + mBase) * 256 + nBase;
    #pragma unroll
    for (int p = 0; p < 2; ++p) {
        __syncthreads();
        ushort_t* Cs = (ushort_t*)lds;     // [128][128] bf16
        #pragma unroll
        for (int mi = 0; mi < 4; ++mi) {
            #pragma unroll
            for (int ni = 0; ni < 4; ++ni) {
                const int rl = (wr << 6) + (mi << 4) + orow;
                const int cl = (wc << 6) + (ni << 4) + ocol;
                #pragma unroll
                for (int r = 0; r < 4; ++r)
                    Cs[(rl + r) * 128 + cl] = f2bf((float)acc[(p << 2) + mi][ni][r]);
            }
        }
        __syncthreads();
        #pragma unroll
        for (int pp = 0; pp < 8; ++pp) {
            const int idx16 = (pp << 8) + tid;
            const int lrow  = idx16 >> 4;
            const int c16   = idx16 & 15;
            const int rowIn = ((lrow >> 6) << 7) + (p << 6) + (lrow & 63);
            const uint4 v = *(const uint4*)(&Cs[(lrow << 7) + (c16 << 3)]);
            *(uint4*)(Yb + sliceBase + (size_t)rowIn * 256 + (c16 << 3)) = v;
        }
    }
}

// ---------------------------------------------------------------------------
// K4 (L1-3): reduce+dequant+postscale (phase 1, b-tile into LDS + cmax atomics)
// -> device barrier -> quantize next level's Bi8 + dq (phase 2).
__global__ __launch_bounds__(256) void reduceQuant(const ushort_t* __restrict__ Yb,
    const float* __restrict__ u, const float* __restrict__ v,
    const float* __restrict__ s, const float* __restrict__ rinv,
    float* __restrict__ hop_out, float* __restrict__ walk_out,
    const float* __restrict__ dq, float* __restrict__ cmaxN,
    char* __restrict__ Bi8, float* __restrict__ dqN, uint_t* __restrict__ ctr)
{
    const int j0 = (blockIdx.x & 127) << 6;
    const int c0 = (blockIdx.x >> 7) << 6;
    const bool hop = (c0 < 128);
    __shared__ float tile[64][65];
    __shared__ uint_t cm[64];
    const int tid = threadIdx.x;
    if (tid < 64) cm[tid] = 0;
    __syncthreads();
    const int cg = tid & 15, jr = tid >> 4;
    const size_t SL = (size_t)NN * 256;
    const float4 dqv = ((const float4*)dq)[(c0 >> 2) + cg];
    float lm0 = 0.f, lm1 = 0.f, lm2 = 0.f, lm3 = 0.f;
    #pragma unroll
    for (int it = 0; it < 4; ++it) {
        const int jl = jr + (it << 4);
        const int j  = j0 + jl;
        const int c  = c0 + (cg << 2);
        const ushort_t* p = Yb + ((size_t)j << 8) + c;
        float e0 = 0.f, e1 = 0.f, e2 = 0.f, e3 = 0.f;
        #pragma unroll
        for (int kss = 0; kss < KS; ++kss) {
            const uint2 q = *(const uint2*)(p + kss * SL);
            e0 += bf2f(q.x & 0xffffu);
            e1 += __uint_as_float(q.x & 0xffff0000u);
            e2 += bf2f(q.y & 0xffffu);
            e3 += __uint_as_float(q.y & 0xffff0000u);
        }
        e0 *= dqv.x; e1 *= dqv.y; e2 *= dqv.z; e3 *= dqv.w;
        float4 o; float scale;
        if (hop) {
            const float si = s[j], si2 = si * si;
            const float4 uu = ((const float4*)u)[((size_t)j << 5) + (c >> 2)];
            o.x = si * e0 + si2 * uu.x;  o.y = si * e1 + si2 * uu.y;
            o.z = si * e2 + si2 * uu.z;  o.w = si * e3 + si2 * uu.w;
            ((float4*)hop_out)[((size_t)j << 5) + (c >> 2)] = o;
            scale = si;
        } else {
            const int cw = c - 128;
            const float4 vv = ((const float4*)v)[((size_t)j << 5) + (cw >> 2)];
            o.x = 0.5f * (vv.x + e0);  o.y = 0.5f * (vv.y + e1);
            o.z = 0.5f * (vv.z + e2);  o.w = 0.5f * (vv.w + e3);
            ((float4*)walk_out)[((size_t)j << 5) + (cw >> 2)] = o;
            scale = rinv[j];
        }
        const float b0 = scale * o.x, b1 = scale * o.y;
        const float b2 = scale * o.z, b3 = scale * o.w;
        const int clb = cg << 2;
        tile[jl][clb + 0] = b0;  tile[jl][clb + 1] = b1;
        tile[jl][clb + 2] = b2;  tile[jl][clb + 3] = b3;
        lm0 = fmaxf(lm0, fabsf(b0));  lm1 = fmaxf(lm1, fabsf(b1));
        lm2 = fmaxf(lm2, fabsf(b2));  lm3 = fmaxf(lm3, fabsf(b3));
    }
    atomicMax(&cm[(cg << 2) + 0], __float_as_uint(lm0));
    atomicMax(&cm[(cg << 2) + 1], __float_as_uint(lm1));
    atomicMax(&cm[(cg << 2) + 2], __float_as_uint(lm2));
    atomicMax(&cm[(cg << 2) + 3], __float_as_uint(lm3));
    __syncthreads();
    if (tid < 64) atomicMax((uint_t*)&cmaxN[c0 + tid], cm[tid]);
    grid_barrier(ctr);
    // phase 2: quantize the b-tile (still in LDS) with the global colmax.
    const int cl = tid & 63, jq = tid >> 6;
    const float cmv = cmax_read(&cmaxN[c0 + cl]);
    const float rs = cmv > 0.f ? 127.f / cmv : 0.f;
    uint_t w4[4];
    #pragma unroll
    for (int g = 0; g < 4; ++g) {
        uint_t wv = 0;
        #pragma unroll
        for (int b = 0; b < 4; ++b) {
            int q = __float2int_rn(tile[(jq << 4) + (g << 2) + b][cl] * rs);
            q = q > 127 ? 127 : (q < -127 ? -127 : q);
            wv |= ((uint_t)(q & 0xff)) << (8 * b);
        }
        w4[g] = wv;
    }
    uint4 st; st.x = w4[0]; st.y = w4[1]; st.z = w4[2]; st.w = w4[3];
    *(uint4*)(Bi8 + ((size_t)(c0 + cl) << 13) + j0 + (jq << 4)) = st;
    if ((blockIdx.x & 127) == 0 && tid < 64)
        dqN[c0 + tid] = cmv * (1.f / 16129.f);
}

// ---------------------------------------------------------------------------
// K4b (L4): walk-half reduce only (no quant, no barrier).
__global__ __launch_bounds__(256) void reduce4(const ushort_t* __restrict__ Yb,
    const float* __restrict__ v, const float* __restrict__ dq,
    float* __restrict__ walk_out)
{
    const int j0 = (blockIdx.x & 127) << 6;
    const int c0 = ((blockIdx.x >> 7) + 2) << 6;
    const int cg = threadIdx.x & 15, jr = threadIdx.x >> 4;
    const size_t SL = (size_t)NN * 256;
    const float4 dqv = ((const float4*)dq)[(c0 >> 2) + cg];
    #pragma unroll
    for (int it = 0; it < 4; ++it) {
        const int jl = jr + (it << 4);
        const int j  = j0 + jl;
        const int c  = c0 + (cg << 2);
        const ushort_t* p = Yb + ((size_t)j << 8) + c;
        float e0 = 0.f, e1 = 0.f, e2 = 0.f, e3 = 0.f;
        #pragma unroll
        for (int kss = 0; kss < KS; ++kss) {
            const uint2 q = *(const uint2*)(p + kss * SL);
            e0 += bf2f(q.x & 0xffffu);
            e1 += __uint_as_float(q.x & 0xffff0000u);
            e2 += bf2f(q.y & 0xffffu);
            e3 += __uint_as_float(q.y & 0xffff0000u);
        }
        const int cw = c - 128;
        const float4 vv = ((const float4*)v)[((size_t)j << 5) + (cw >> 2)];
        float4 o;
        o.x = 0.5f * (vv.x + e0 * dqv.x);  o.y = 0.5f * (vv.y + e1 * dqv.y);
        o.z = 0.5f * (vv.z + e2 * dqv.z);  o.w = 0.5f * (vv.w + e3 * dqv.w);
        ((float4*)walk_out)[((size_t)j << 5) + (cw >> 2)] = o;
    }
}

// ---------------------------------------------------------------------------
// K5: fused attn + 2-layer MLP. 16 nodes/block, 16 thr/node (8 k's each).
// Node-local chain: hp stays in LDS; W1 then W2 staged into same Ws region
// (stride 132 floats -> 2-way max bank alias; 76 KB LDS -> 2 blocks/CU).
__global__ __launch_bounds__(256) void attn_mlp(const float* __restrict__ X,
    const float* __restrict__ hA, const float* __restrict__ hA2, const float* __restrict__ hA3,
    const float* __restrict__ px, const float* __restrict__ p2x, const float* __restrict__ p4x,
    const float* __restrict__ a, const float* __restrict__ W1, const float* __restrict__ b1,
    const float* __restrict__ W2, const float* __restrict__ b2, float* __restrict__ out)
{
    __shared__ float Ws[128 * 132];
    __shared__ float Hs[16 * 132];
    const int tid = threadIdx.x;
    const int node0 = blockIdx.x << 4;
    const int n = tid >> 4, c = tid & 15;
    // stage W1 (attn compute below hides the load latency)
    for (int rr = 0; rr < 64; ++rr) {
        const int idx = rr * 256 + tid;
        Ws[(idx >> 7) * 132 + (idx & 127)] = W1[idx];
    }
    // ---- attention for node node0+n, k in [c*8, c*8+8) ----
    const size_t base = ((size_t)(node0 + n)) << 7;
    const int k0 = c << 3;
    float f[6][8];
    float e[6] = {0.f, 0.f, 0.f, 0.f, 0.f, 0.f};
    #pragma unroll
    for (int h = 0; h < 8; ++h) {
        const int k = k0 + h;
        const float a2 = a[128 + k];
        const float x   = X[base + k];
        const float t1  = leaky(hA [base + k]);
        const float t2  = leaky(hA2[base + k]);
        const float t3  = leaky(hA3[base + k]);
        const float pk  = px [base + k];
        const float p2k = p2x[base + k];
        const float p4k = p4x[base + k];
        const float s1 = fabsf(x - pk);
        const float s2 = fabsf(pk - p2k);
        const float s3 = fabsf(p2k - p4k);
        f[0][h] = t1; f[1][h] = t2; f[2][h] = t3;
        f[3][h] = s1; f[4][h] = s2; f[5][h] = s3;
        e[0] += fmaxf(t1, 0.f) * a2;
        e[1] += fmaxf(t2, 0.f) * a2;
        e[2] += fmaxf(t3, 0.f) * a2;
        e[3] += s1 * a2;
        e[4] += s2 * a2;
        e[5] += s3 * a2;
    }
    #pragma unroll
    for (int ss = 0; ss < 6; ++ss) {
        #pragma unroll
        for (int off = 8; off; off >>= 1) e[ss] += __shfl_xor(e[ss], off);
    }
    float mx = e[0];
    #pragma unroll
    for (int ss = 1; ss < 6; ++ss) mx = fmaxf(mx, e[ss]);
    float at[6], sum = 0.f;
    #pragma unroll
    for (int ss = 0; ss < 6; ++ss) { at[ss] = expf(e[ss] - mx); sum += at[ss]; }
    const float inv = 1.f / (6.f * sum);
    #pragma unroll
    for (int h = 0; h < 8; ++h) {
        float o = 0.f;
        #pragma unroll
        for (int ss = 0; ss < 6; ++ss) o += at[ss] * f[ss][h];
        Hs[n * 132 + k0 + h] = o * inv;
    }
    __syncthreads();
    // ---- MLP layer 1 ----
    float acc[8] = {};
    for (int k4 = 0; k4 < 32; ++k4) {
        const float4 h4 = *(const float4*)(&Hs[n * 132 + (k4 << 2)]);
        #pragma unroll
        for (int r = 0; r < 8; ++r) {
            const float4 w4 = *(const float4*)(&Ws[(c + (r << 4)) * 132 + (k4 << 2)]);
            acc[r] += h4.x * w4.x + h4.y * w4.y + h4.z * w4.z + h4.w * w4.w;
        }
    }
    __syncthreads();            // layer-1 reads of Hs/Ws complete
    #pragma unroll
    for (int r = 0; r < 8; ++r) {
        const int o = c + (r << 4);
        Hs[n * 132 + o] = leaky(acc[r] + b1[o]);
    }
    for (int rr = 0; rr < 64; ++rr) {     // stage W2 over W1
        const int idx = rr * 256 + tid;
        Ws[(idx >> 7) * 132 + (idx & 127)] = W2[idx];
    }
    __syncthreads();
    // ---- MLP layer 2 ----
    float acc2[8] = {};
    for (int k4 = 0; k4 < 32; ++k4) {
        const float4 h4 = *(const float4*)(&Hs[n * 132 + (k4 << 2)]);
        #pragma unroll
        for (int r = 0; r < 8; ++r) {
            const float4 w4 = *(const float4*)(&Ws[(c + (r << 4)) * 132 + (k4 << 2)]);
            acc2[r] += h4.x * w4.x + h4.y * w4.y + h4.z * w4.z + h4.w * w4.w;
        }
    }
    #pragma unroll
    for (int r = 0; r < 8; ++r) {
        const int o = c + (r << 4);
        out[base + o] = leaky(acc2[r] + b2[o]);
    }
}

// ---------------------------------------------------------------------------
extern "C" void kernel_launch(void* const* d_in, const int* in_sizes, int n_in,
                              void* d_out, int out_size, void* d_ws, size_t ws_size,
                              hipStream_t stream)
{
    const float* X   = (const float*)d_in[0];
    const float* adj = (const float*)d_in[1];
    const float* W1  = (const float*)d_in[2];
    const float* b1  = (const float*)d_in[3];
    const float* W2  = (const float*)d_in[4];
    const float* b2  = (const float*)d_in[5];
    const float* a   = (const float*)d_in[6];
    float* out = (float*)d_out;

    // Workspace layout (~132 MB)
    char* ws = (char*)d_ws;
    char*     adjq = ws;                                   //  64 MB i8 adj
    char*     Bi8  = ws + 67108864ull;                     //   2 MB i8 B
    ushort_t* Yb   = (ushort_t*)(ws + 69206016ull);        //  32 MB bf16 partials
    float* hA  = (float*)(ws + 102760448ull);              //   4 MB each below
    float* hA2 = hA  + 1048576;
    float* hA3 = hA2 + 1048576;
    float* px  = hA3 + 1048576;
    float* p2x = px  + 1048576;
    float* p3x = p2x + 1048576;
    float* p4x = p3x + 1048576;
    float* sbuf  = p4x + 1048576;                          // 32 KB (row scales)
    float* rinvb = sbuf + 8192;                            // 32 KB
    float* cmaxb = rinvb + 8192;                           // cmax[1024] dq[256] ctr[...]
    float* dq    = cmaxb + 1024;
    uint_t* ctr  = (uint_t*)(cmaxb + 1280);                // 4 counters (zeroed w/ cmax)
    float* cmax1 = cmaxb, *cmax2 = cmaxb + 256, *cmax3 = cmaxb + 512, *cmax4 = cmaxb + 768;

    conv_rowsum<<<8192, 256, 0, stream>>>(adj, adjq, sbuf, rinvb, cmaxb);

    // Level 1
    quantX<<<512, 256, 0, stream>>>(X, sbuf, rinvb, cmax1, Bi8, dq, ctr + 0);
    gemm_i8<<<256, 512, 0, stream>>>(adjq, Bi8, Yb);
    reduceQuant<<<512, 256, 0, stream>>>(Yb, X, X, sbuf, rinvb,
                                         hA, px, dq, cmax2, Bi8, dq, ctr + 1);
    // Level 2
    gemm_i8<<<256, 512, 0, stream>>>(adjq, Bi8, Yb);
    reduceQuant<<<512, 256, 0, stream>>>(Yb, hA, px, sbuf, rinvb,
                                         hA2, p2x, dq, cmax3, Bi8, dq, ctr + 2);
    // Level 3
    gemm_i8<<<256, 512, 0, stream>>>(adjq, Bi8, Yb);
    reduceQuant<<<512, 256, 0, stream>>>(Yb, hA2, p2x, sbuf, rinvb,
                                         hA3, p3x, dq, cmax4, Bi8, dq, ctr + 3);
    // Level 4 (walk half only)
    gemm_half_i8<<<256, 256, 0, stream>>>(adjq, Bi8, Yb, 1, 1);
    reduce4<<<256, 256, 0, stream>>>(Yb, p3x, dq, p4x);

    attn_mlp<<<512, 256, 0, stream>>>(X, hA, hA2, hA3, px, p2x, p4x, a,
                                      W1, b1, W2, b2, out);
}

// Round 13
// 258.368 us; speedup vs baseline: 2.7218x; 1.7819x over previous
//
#include <hip/hip_runtime.h>

typedef unsigned short ushort_t;
typedef unsigned int   uint_t;
typedef int   i32x4 __attribute__((ext_vector_type(4)));

typedef __attribute__((address_space(3))) void lds_void_t;
typedef __attribute__((address_space(1))) void gbl_void_t;

#define NN 8192
#define HH 128
#define KS 8          // K-split factor
#define KLEN 1024     // K elements per split slice
#define NTQ 16        // K-tiles per block (KLEN / 64, i8 BK=64)

__device__ __forceinline__ ushort_t f2bf(float x) {
    uint_t u = __float_as_uint(x);
    u += 0x7fffu + ((u >> 16) & 1u);          // RNE
    return (ushort_t)(u >> 16);
}
__device__ __forceinline__ float bf2f(uint_t lo16) { return __uint_as_float(lo16 << 16); }
__device__ __forceinline__ float leaky(float x) { return x > 0.f ? x : 0.01f * x; }

// ---------------------------------------------------------------------------
// K0: adj f32 -> i8 (round(a*127)) + row sums -> s, rinv.
// Block 0 zeroes the cmax region (replaces the memset dispatch).
__global__ __launch_bounds__(256) void conv_rowsum(const float* __restrict__ adj,
    char* __restrict__ adjq, float* __restrict__ s, float* __restrict__ rinv,
    float* __restrict__ zbase)
{
    const int i = blockIdx.x;
    if (i == 0) {
        ((float4*)zbase)[threadIdx.x] = float4{0.f, 0.f, 0.f, 0.f};  // 1024 floats
    }
    const float4* arow = (const float4*)(adj + ((size_t)i << 13));
    uint_t* brow = (uint_t*)(adjq + ((size_t)i << 13));
    float partial = 0.f;
    for (int t = threadIdx.x; t < 2048; t += 256) {
        const float4 v = arow[t];
        partial += (v.x + v.y) + (v.z + v.w);
        const uint_t q0 = (uint_t)__float2int_rn(v.x * 127.f);
        const uint_t q1 = (uint_t)__float2int_rn(v.y * 127.f);
        const uint_t q2 = (uint_t)__float2int_rn(v.z * 127.f);
        const uint_t q3 = (uint_t)__float2int_rn(v.w * 127.f);
        brow[t] = q0 | (q1 << 8) | (q2 << 16) | (q3 << 24);
    }
    #pragma unroll
    for (int off = 32; off; off >>= 1) partial += __shfl_xor(partial, off);
    __shared__ float ps[4];
    if ((threadIdx.x & 63) == 0) ps[threadIdx.x >> 6] = partial;
    __syncthreads();
    if (threadIdx.x == 0) {
        const float tot = (ps[0] + ps[1]) + (ps[2] + ps[3]);
        s[i]    = rsqrtf(tot + 1.0f);
        rinv[i] = 1.0f / tot;
    }
}

// ---------------------------------------------------------------------------
// K1: per-column max of |b| for level-1 B.
__global__ __launch_bounds__(256) void preMax(const float* __restrict__ u,
    const float* __restrict__ v, const float* __restrict__ s, const float* __restrict__ rinv,
    float* __restrict__ cmax)
{
    const int j0 = (blockIdx.x & 127) << 6;
    const int c0 = (blockIdx.x >> 7) << 6;
    __shared__ uint_t cm[64];
    if (threadIdx.x < 64) cm[threadIdx.x] = 0;
    __syncthreads();
    const int tx = threadIdx.x & 63;
    const int ty = threadIdx.x >> 6;
    float m = 0.f;
    #pragma unroll
    for (int rr = 0; rr < 16; ++rr) {
        const int j = j0 + ty + (rr << 2);
        const int c = c0 + tx;
        const float val = (c < 128) ? s[j] * u[((size_t)j << 7) + c]
                                    : rinv[j] * v[((size_t)j << 7) + (c - 128)];
        m = fmaxf(m, fabsf(val));
    }
    atomicMax(&cm[tx], __float_as_uint(m));
    __syncthreads();
    if (threadIdx.x < 64)
        atomicMax((uint_t*)&cmax[c0 + threadIdx.x], cm[threadIdx.x]);
}

// ---------------------------------------------------------------------------
// K2: build Bi8 with per-column scale 127/cmax[c]; dq[c] = cmax[c]/127^2.
__global__ __launch_bounds__(256) void preQ(const float* __restrict__ u,
    const float* __restrict__ v, const float* __restrict__ s, const float* __restrict__ rinv,
    const float* __restrict__ cmax, char* __restrict__ Bi8, float* __restrict__ dq)
{
    const int j0 = (blockIdx.x & 127) << 6;
    const int c0 = (blockIdx.x >> 7) << 6;
    __shared__ float tile[64][65];
    const int tx = threadIdx.x & 63;
    const int ty = threadIdx.x >> 6;
    #pragma unroll
    for (int rr = 0; rr < 16; ++rr) {
        const int jl = ty + (rr << 2);
        const int j = j0 + jl;
        const int c = c0 + tx;
        tile[jl][tx] = (c < 128) ? s[j] * u[((size_t)j << 7) + c]
                                 : rinv[j] * v[((size_t)j << 7) + (c - 128)];
    }
    __syncthreads();
    const int cl = threadIdx.x & 63;
    const int jq = threadIdx.x >> 6;
    const float cmv = cmax[c0 + cl];
    const float rs = cmv > 0.f ? 127.f / cmv : 0.f;
    uint_t w4[4];
    #pragma unroll
    for (int g = 0; g < 4; ++g) {
        uint_t wv = 0;
        #pragma unroll
        for (int b = 0; b < 4; ++b) {
            int q = __float2int_rn(tile[(jq << 4) + (g << 2) + b][cl] * rs);
            q = q > 127 ? 127 : (q < -127 ? -127 : q);
            wv |= ((uint_t)(q & 0xff)) << (8 * b);
        }
        w4[g] = wv;
    }
    uint4 st; st.x = w4[0]; st.y = w4[1]; st.z = w4[2]; st.w = w4[3];
    *(uint4*)(Bi8 + ((size_t)(c0 + cl) << 13) + j0 + (jq << 4)) = st;
    if ((blockIdx.x & 127) == 0 && threadIdx.x < 64)
        dq[c0 + threadIdx.x] = cmax[c0 + threadIdx.x] * (1.f / 16129.f);
}

// ---------------------------------------------------------------------------
// K3a: ring-4 i8 GEMM (R10-proven). BM=BN=256, BK=64B, 8 waves 2Mx4N,
// 4-deep 32KB slots, 128 KiB LDS.
#define WAITB(S) do {                                         \
    asm volatile("s_waitcnt " S ::: "memory");                \
    __builtin_amdgcn_sched_barrier(0);                        \
    __builtin_amdgcn_s_barrier();                             \
    __builtin_amdgcn_sched_barrier(0);                        \
} while (0)

__global__ __launch_bounds__(512, 2) void gemm_i8(const char* __restrict__ A,
    const char* __restrict__ Bt, ushort_t* __restrict__ Yb)
{
    __shared__ char lds[4 * 32768];       // ring: [4][A 16KB | B 16KB]
    const int bid = blockIdx.x;
    const int mb = bid & 31;
    const int ks = bid >> 5;
    const size_t mBase = (size_t)mb * 256;
    const int tid = threadIdx.x;
    const int w = tid >> 6, l = tid & 63;
    const int wr = w >> 2, wc = w & 3;
    const int frow = l & 15, fk = l >> 4;
    const int fsl = ((fk ^ ((frow >> 1) & 3)) << 4);
    const int srow = l >> 2;
    const int skoff = (((l & 3) ^ ((l >> 3) & 3)) << 4);
    const int kBeg = ks << 10;

    i32x4 acc[8][4] = {};

    auto STAGE = [&](int t) {
        const int k0 = kBeg + (t << 6);
        char* base = &lds[(t & 3) << 15];
        #pragma unroll
        for (int q = 0; q < 2; ++q) {
            const int c = (w << 1) + q;
            const int row = (c << 4) + srow;
            __builtin_amdgcn_global_load_lds(
                (const gbl_void_t*)(A + ((mBase + row) << 13) + k0 + skoff),
                (lds_void_t*)(base + (c << 10)), 16, 0, 0);
            __builtin_amdgcn_global_load_lds(
                (const gbl_void_t*)(Bt + ((size_t)row << 13) + k0 + skoff),
                (lds_void_t*)(base + 16384 + (c << 10)), 16, 0, 0);
        }
    };
    auto COMPUTE = [&](int T) {
        const char* buf = &lds[(T & 3) << 15];
        i32x4 av[8], bv[4];
        #pragma unroll
        for (int mi = 0; mi < 8; ++mi) {
            const int row = (wr << 7) + (mi << 4) + frow;
            av[mi] = *(const i32x4*)(buf + (row << 6) + fsl);
        }
        #pragma unroll
        for (int ni = 0; ni < 4; ++ni) {
            const int col = (wc << 6) + (ni << 4) + frow;
            bv[ni] = *(const i32x4*)(buf + 16384 + (col << 6) + fsl);
        }
        __builtin_amdgcn_s_setprio(1);
        #pragma unroll
        for (int mi = 0; mi < 8; ++mi)
            #pragma unroll
            for (int ni = 0; ni < 4; ++ni)
                acc[mi][ni] = __builtin_amdgcn_mfma_i32_16x16x64_i8(
                    av[mi], bv[ni], acc[mi][ni], 0, 0, 0);
        __builtin_amdgcn_s_setprio(0);
    };

    STAGE(0); STAGE(1); STAGE(2);
    #pragma unroll 1
    for (int T = 0; T < NTQ - 3; ++T) {
        WAITB("vmcnt(8)");
        STAGE(T + 3);
        COMPUTE(T);
    }
    WAITB("vmcnt(8)"); COMPUTE(NTQ - 3);
    WAITB("vmcnt(4)"); COMPUTE(NTQ - 2);
    WAITB("vmcnt(0)"); COMPUTE(NTQ - 1);
    __syncthreads();

    // Epilogue: i32 -> f32 -> bf16 Cs[256][256] -> coalesced stores.
    ushort_t* Cs = (ushort_t*)lds;
    const int orow = (l >> 4) << 2;
    const int ocol = l & 15;
    #pragma unroll
    for (int mi = 0; mi < 8; ++mi) {
        #pragma unroll
        for (int ni = 0; ni < 4; ++ni) {
            const int rl = (wr << 7) + (mi << 4) + orow;
            const int cl = (wc << 6) + (ni << 4) + ocol;
            #pragma unroll
            for (int r = 0; r < 4; ++r)
                Cs[(rl + r) * 256 + cl] = f2bf((float)acc[mi][ni][r]);
        }
    }
    __syncthreads();
    const size_t sliceBase = ((size_t)ks * NN + mBase) * 256;
    #pragma unroll
    for (int p = 0; p < 16; ++p) {
        const int idx16 = (p << 9) + tid;
        const int row   = idx16 >> 5;
        const int c16   = idx16 & 31;
        const uint4 v = *(const uint4*)(&Cs[(row << 8) + (c16 << 3)]);
        *(uint4*)(Yb + sliceBase + (size_t)row * 256 + (c16 << 3)) = v;
    }
}

// ---------------------------------------------------------------------------
// K3b (L4): half-width i8 GEMM. BM=256 BN=128, 4 waves, ring-2 (48KB).
__global__ __launch_bounds__(256, 2) void gemm_half_i8(const char* __restrict__ A,
    const char* __restrict__ Bt, ushort_t* __restrict__ Yb, int nbOff, int nbCount)
{
    __shared__ char lds[2 * 24576];       // per buf: A 16KB | B 8KB
    const int bid  = blockIdx.x;
    const int mb   = bid & 31;
    const int rest = bid >> 5;
    const int nb   = nbOff + (rest % nbCount);
    const int ks   = rest / nbCount;
    const size_t mBase = (size_t)mb * 256;
    const size_t nBase = (size_t)nb * 128;
    const int tid = threadIdx.x;
    const int w = tid >> 6, l = tid & 63;
    const int wr = w >> 1, wc = w & 1;
    const int frow = l & 15, fk = l >> 4;
    const int fsl = ((fk ^ ((frow >> 1) & 3)) << 4);
    const int srow = l >> 2;
    const int skoff = (((l & 3) ^ ((l >> 3) & 3)) << 4);
    const int kBeg = ks << 10;

    i32x4 acc[8][4] = {};

    auto STAGE = [&](int t) {
        const int k0 = kBeg + (t << 6);
        char* base = &lds[(t & 1) * 24576];
        #pragma unroll
        for (int q = 0; q < 4; ++q) {
            const int c = (w << 2) + q;
            const int row = (c << 4) + srow;
            __builtin_amdgcn_global_load_lds(
                (const gbl_void_t*)(A + ((mBase + row) << 13) + k0 + skoff),
                (lds_void_t*)(base + (c << 10)), 16, 0, 0);
        }
        #pragma unroll
        for (int q = 0; q < 2; ++q) {
            const int c = (w << 1) + q;
            const int row = (c << 4) + srow;
            __builtin_amdgcn_global_load_lds(
                (const gbl_void_t*)(Bt + ((nBase + row) << 13) + k0 + skoff),
                (lds_void_t*)(base + 16384 + (c << 10)), 16, 0, 0);
        }
    };

    STAGE(0);
    __syncthreads();
    #pragma unroll 1
    for (int T = 0; T < NTQ; ++T) {
        if (T + 1 < NTQ) STAGE(T + 1);
        const char* buf = &lds[(T & 1) * 24576];
        i32x4 av[8], bv[4];
        #pragma unroll
        for (int mi = 0; mi < 8; ++mi) {
            const int row = (wr << 7) + (mi << 4) + frow;
            av[mi] = *(const i32x4*)(buf + (row << 6) + fsl);
        }
        #pragma unroll
        for (int ni = 0; ni < 4; ++ni) {
            const int col = (wc << 6) + (ni << 4) + frow;
            bv[ni] = *(const i32x4*)(buf + 16384 + (col << 6) + fsl);
        }
        __builtin_amdgcn_s_setprio(1);
        #pragma unroll
        for (int mi = 0; mi < 8; ++mi)
            #pragma unroll
            for (int ni = 0; ni < 4; ++ni)
                acc[mi][ni] = __builtin_amdgcn_mfma_i32_16x16x64_i8(
                    av[mi], bv[ni], acc[mi][ni], 0, 0, 0);
        __builtin_amdgcn_s_setprio(0);
        __syncthreads();
    }

    const int orow = (l >> 4) << 2;
    const int ocol = l & 15;
    const size_t sliceBase = ((size_t)ks * NN + mBase) * 256 + nBase;
    #pragma unroll
    for (int p = 0; p < 2; ++p) {
        __syncthreads();
        ushort_t* Cs = (ushort_t*)lds;     // [128][128] bf16
        #pragma unroll
        for (int mi = 0; mi < 4; ++mi) {
            #pragma unroll
            for (int ni = 0; ni < 4; ++ni) {
                const int rl = (wr << 6) + (mi << 4) + orow;
                const int cl = (wc << 6) + (ni << 4) + ocol;
                #pragma unroll
                for (int r = 0; r < 4; ++r)
                    Cs[(rl + r) * 128 + cl] = f2bf((float)acc[(p << 2) + mi][ni][r]);
            }
        }
        __syncthreads();
        #pragma unroll
        for (int pp = 0; pp < 8; ++pp) {
            const int idx16 = (pp << 8) + tid;
            const int lrow  = idx16 >> 4;
            const int c16   = idx16 & 15;
            const int rowIn = ((lrow >> 6) << 7) + (p << 6) + (lrow & 63);
            const uint4 v = *(const uint4*)(&Cs[(lrow << 7) + (c16 << 3)]);
            *(uint4*)(Yb + sliceBase + (size_t)rowIn * 256 + (c16 << 3)) = v;
        }
    }
}

// ---------------------------------------------------------------------------
// K4: reduce KS bf16 partials, dequant by dq[c], postscale; track next-level
// per-column max into cmaxN (L1-3).
__global__ __launch_bounds__(256) void reduce_post(const ushort_t* __restrict__ Yb,
    const float* __restrict__ u, const float* __restrict__ v,
    const float* __restrict__ s, const float* __restrict__ rinv,
    float* __restrict__ hop_out, float* __restrict__ walk_out,
    const float* __restrict__ dq, float* __restrict__ cmaxN, int c0Off)
{
    const int j0 = (blockIdx.x & 127) << 6;
    const int c0 = ((blockIdx.x >> 7) + c0Off) << 6;
    const bool hop = (c0 < 128);
    if (hop && hop_out == nullptr) return;
    __shared__ uint_t cm[64];
    if (cmaxN && threadIdx.x < 64) cm[threadIdx.x] = 0;
    if (cmaxN) __syncthreads();
    const int cg = threadIdx.x & 15;
    const int jr = threadIdx.x >> 4;
    const size_t SL = (size_t)NN * 256;
    const float4 dqv = ((const float4*)dq)[(c0 >> 2) + cg];
    float lm0 = 0.f, lm1 = 0.f, lm2 = 0.f, lm3 = 0.f;
    #pragma unroll
    for (int it = 0; it < 4; ++it) {
        const int jl = jr + (it << 4);
        const int j  = j0 + jl;
        const int c  = c0 + (cg << 2);
        const ushort_t* p = Yb + ((size_t)j << 8) + c;
        float e0 = 0.f, e1 = 0.f, e2 = 0.f, e3 = 0.f;
        #pragma unroll
        for (int kss = 0; kss < KS; ++kss) {
            const uint2 q = *(const uint2*)(p + kss * SL);
            e0 += bf2f(q.x & 0xffffu);
            e1 += __uint_as_float(q.x & 0xffff0000u);
            e2 += bf2f(q.y & 0xffffu);
            e3 += __uint_as_float(q.y & 0xffff0000u);
        }
        e0 *= dqv.x; e1 *= dqv.y; e2 *= dqv.z; e3 *= dqv.w;
        float4 o; float scale;
        if (hop) {
            const float si = s[j], si2 = si * si;
            const float4 uu = ((const float4*)u)[((size_t)j << 5) + (c >> 2)];
            o.x = si * e0 + si2 * uu.x;  o.y = si * e1 + si2 * uu.y;
            o.z = si * e2 + si2 * uu.z;  o.w = si * e3 + si2 * uu.w;
            ((float4*)hop_out)[((size_t)j << 5) + (c >> 2)] = o;
            scale = si;
        } else {
            const int cw = c - 128;
            const float4 vv = ((const float4*)v)[((size_t)j << 5) + (cw >> 2)];
            o.x = 0.5f * (vv.x + e0);  o.y = 0.5f * (vv.y + e1);
            o.z = 0.5f * (vv.z + e2);  o.w = 0.5f * (vv.w + e3);
            ((float4*)walk_out)[((size_t)j << 5) + (cw >> 2)] = o;
            scale = rinv[j];
        }
        if (cmaxN) {
            lm0 = fmaxf(lm0, fabsf(scale * o.x));
            lm1 = fmaxf(lm1, fabsf(scale * o.y));
            lm2 = fmaxf(lm2, fabsf(scale * o.z));
            lm3 = fmaxf(lm3, fabsf(scale * o.w));
        }
    }
    if (cmaxN) {
        atomicMax(&cm[(cg << 2) + 0], __float_as_uint(lm0));
        atomicMax(&cm[(cg << 2) + 1], __float_as_uint(lm1));
        atomicMax(&cm[(cg << 2) + 2], __float_as_uint(lm2));
        atomicMax(&cm[(cg << 2) + 3], __float_as_uint(lm3));
        __syncthreads();
        if (threadIdx.x < 64)
            atomicMax((uint_t*)&cmaxN[c0 + threadIdx.x], cm[threadIdx.x]);
    }
}

// ---------------------------------------------------------------------------
// K5: 6-way attention fusion WITH inline L4 reduce (replaces reduce4).
// p4x[node][k] = 0.5*(p3x[node][k] + dq[128+k] * sum_ks Yb[ks][node][128+k])
// Same summation order as the old reduce4 -> bit-identical results.
__global__ __launch_bounds__(256) void fuse_attn(const float* __restrict__ X,
    const float* __restrict__ hA, const float* __restrict__ hA2, const float* __restrict__ hA3,
    const float* __restrict__ px, const float* __restrict__ p2x, const float* __restrict__ p3x,
    const ushort_t* __restrict__ Yb, const float* __restrict__ dq,
    const float* __restrict__ a, float* __restrict__ hp)
{
    const int w = threadIdx.x >> 6, l = threadIdx.x & 63;
    const size_t i = (size_t)blockIdx.x * 4 + w;
    const size_t base = i << 7;
    const size_t SL = (size_t)NN * 256;
    float f[6][2];
    float e[6] = {0.f, 0.f, 0.f, 0.f, 0.f, 0.f};
    #pragma unroll
    for (int h = 0; h < 2; ++h) {
        const int k = l + (h << 6);
        const float a2 = a[128 + k];
        const float x   = X[base + k];
        const float t1  = leaky(hA [base + k]);
        const float t2  = leaky(hA2[base + k]);
        const float t3  = leaky(hA3[base + k]);
        const float pk  = px [base + k];
        const float p2k = p2x[base + k];
        // inline L4 reduce: p4k from Yb walk columns
        const ushort_t* yp = Yb + (i << 8) + 128 + k;
        float ew = 0.f;
        #pragma unroll
        for (int kss = 0; kss < KS; ++kss) ew += bf2f(yp[kss * SL]);
        const float p4k = 0.5f * (p3x[base + k] + ew * dq[128 + k]);
        const float s1 = fabsf(x - pk);
        const float s2 = fabsf(pk - p2k);
        const float s3 = fabsf(p2k - p4k);
        f[0][h] = t1; f[1][h] = t2; f[2][h] = t3;
        f[3][h] = s1; f[4][h] = s2; f[5][h] = s3;
        e[0] += fmaxf(t1, 0.f) * a2;
        e[1] += fmaxf(t2, 0.f) * a2;
        e[2] += fmaxf(t3, 0.f) * a2;
        e[3] += s1 * a2;
        e[4] += s2 * a2;
        e[5] += s3 * a2;
    }
    #pragma unroll
    for (int ss = 0; ss < 6; ++ss) {
        #pragma unroll
        for (int off = 32; off; off >>= 1) e[ss] += __shfl_xor(e[ss], off);
    }
    float mx = e[0];
    #pragma unroll
    for (int ss = 1; ss < 6; ++ss) mx = fmaxf(mx, e[ss]);
    float at[6], sum = 0.f;
    #pragma unroll
    for (int ss = 0; ss < 6; ++ss) { at[ss] = expf(e[ss] - mx); sum += at[ss]; }
    const float inv = 1.f / (6.f * sum);
    #pragma unroll
    for (int h = 0; h < 2; ++h) {
        float o = 0.f;
        #pragma unroll
        for (int ss = 0; ss < 6; ++ss) o += at[ss] * f[ss][h];
        hp[base + l + (h << 6)] = o * inv;
    }
}

// ---------------------------------------------------------------------------
// K6: out = leaky(Hm @ W^T + b), f32 (proven single-layer, 2 blocks/CU).
__global__ __launch_bounds__(256) void mlp(const float* __restrict__ Hm,
    const float* __restrict__ W, const float* __restrict__ b, float* __restrict__ out)
{
    __shared__ float Ws[128 * 140];
    __shared__ float Hs[16 * 140];
    const int node0 = blockIdx.x << 4;
    for (int rr = 0; rr < 64; ++rr) {
        const int idx = rr * 256 + threadIdx.x;
        Ws[(idx >> 7) * 140 + (idx & 127)] = W[idx];
    }
    #pragma unroll
    for (int rr = 0; rr < 8; ++rr) {
        const int idx = rr * 256 + threadIdx.x;
        Hs[(idx >> 7) * 140 + (idx & 127)] = Hm[((size_t)node0 << 7) + idx];
    }
    __syncthreads();
    const int c = threadIdx.x & 15;
    const int n = threadIdx.x >> 4;
    float acc[8] = {};
    for (int k4 = 0; k4 < 32; ++k4) {
        const float4 h4 = *(const float4*)(&Hs[n * 140 + (k4 << 2)]);
        #pragma unroll
        for (int r = 0; r < 8; ++r) {
            const float4 w4 = *(const float4*)(&Ws[(c + (r << 4)) * 140 + (k4 << 2)]);
            acc[r] += h4.x * w4.x + h4.y * w4.y + h4.z * w4.z + h4.w * w4.w;
        }
    }
    const size_t obase = ((size_t)(node0 + n)) << 7;
    #pragma unroll
    for (int r = 0; r < 8; ++r) {
        const int o = c + (r << 4);
        out[obase + o] = leaky(acc[r] + b[o]);
    }
}

// ---------------------------------------------------------------------------
extern "C" void kernel_launch(void* const* d_in, const int* in_sizes, int n_in,
                              void* d_out, int out_size, void* d_ws, size_t ws_size,
                              hipStream_t stream)
{
    const float* X   = (const float*)d_in[0];
    const float* adj = (const float*)d_in[1];
    const float* W1  = (const float*)d_in[2];
    const float* b1  = (const float*)d_in[3];
    const float* W2  = (const float*)d_in[4];
    const float* b2  = (const float*)d_in[5];
    const float* a   = (const float*)d_in[6];
    float* out = (float*)d_out;

    // Workspace layout (~132 MB)
    char* ws = (char*)d_ws;
    char*     adjq = ws;                                   //  64 MB i8 adj
    char*     Bi8  = ws + 67108864ull;                     //   2 MB i8 B
    ushort_t* Yb   = (ushort_t*)(ws + 69206016ull);        //  32 MB bf16 partials
    float* hA  = (float*)(ws + 102760448ull);              //   4 MB each below
    float* hA2 = hA  + 1048576;
    float* hA3 = hA2 + 1048576;
    float* px  = hA3 + 1048576;
    float* p2x = px  + 1048576;
    float* p3x = p2x + 1048576;
    float* p4x = p3x + 1048576;   // free buffer -> used as hp
    float* sbuf  = p4x + 1048576;                          // 32 KB
    float* rinvb = sbuf + 8192;                            // 32 KB
    float* cmaxb = rinvb + 8192;                           // 4 x 256 f32
    float* dq    = cmaxb + 1024;                           // 256 f32
    float* cmax1 = cmaxb, *cmax2 = cmaxb + 256, *cmax3 = cmaxb + 512, *cmax4 = cmaxb + 768;
    float* hp   = p4x;            // fuse_attn now READS Yb, so hp can't overlay it
    float* out1 = (float*)(ws + 69206016ull + 4194304ull); // inside Yb (dead by mlp time)

    conv_rowsum<<<8192, 256, 0, stream>>>(adj, adjq, sbuf, rinvb, cmaxb);

    // Level 1
    preMax<<<512, 256, 0, stream>>>(X, X, sbuf, rinvb, cmax1);
    preQ  <<<512, 256, 0, stream>>>(X, X, sbuf, rinvb, cmax1, Bi8, dq);
    gemm_i8<<<256, 512, 0, stream>>>(adjq, Bi8, Yb);
    reduce_post<<<512, 256, 0, stream>>>(Yb, X, X, sbuf, rinvb,
                                         hA, px, dq, cmax2, 0);
    // Level 2
    preQ  <<<512, 256, 0, stream>>>(hA, px, sbuf, rinvb, cmax2, Bi8, dq);
    gemm_i8<<<256, 512, 0, stream>>>(adjq, Bi8, Yb);
    reduce_post<<<512, 256, 0, stream>>>(Yb, hA, px, sbuf, rinvb,
                                         hA2, p2x, dq, cmax3, 0);
    // Level 3
    preQ  <<<512, 256, 0, stream>>>(hA2, p2x, sbuf, rinvb, cmax3, Bi8, dq);
    gemm_i8<<<256, 512, 0, stream>>>(adjq, Bi8, Yb);
    reduce_post<<<512, 256, 0, stream>>>(Yb, hA2, p2x, sbuf, rinvb,
                                         hA3, p3x, dq, cmax4, 0);
    // Level 4 (walk half only; reduce folded into fuse_attn)
    preQ  <<<512, 256, 0, stream>>>(hA3, p3x, sbuf, rinvb, cmax4, Bi8, dq);
    gemm_half_i8<<<256, 256, 0, stream>>>(adjq, Bi8, Yb, 1, 1);

    fuse_attn<<<2048, 256, 0, stream>>>(X, hA, hA2, hA3, px, p2x, p3x,
                                        Yb, dq, a, hp);
    mlp<<<512, 256, 0, stream>>>(hp, W1, b1, out1);
    mlp<<<512, 256, 0, stream>>>(out1, W2, b2, out);
}

// Round 14
// 250.254 us; speedup vs baseline: 2.8100x; 1.0324x over previous
//
#include <hip/hip_runtime.h>

typedef unsigned short ushort_t;
typedef unsigned int   uint_t;
typedef int   i32x4 __attribute__((ext_vector_type(4)));

typedef __attribute__((address_space(3))) void lds_void_t;
typedef __attribute__((address_space(1))) void gbl_void_t;

#define NN 8192
#define HH 128
#define KS 8          // K-split factor
#define KLEN 1024     // K elements per split slice
#define NTQ 16        // K-tiles per block (KLEN / 64, i8 BK=64)

__device__ __forceinline__ ushort_t f2bf(float x) {
    uint_t u = __float_as_uint(x);
    u += 0x7fffu + ((u >> 16) & 1u);          // RNE
    return (ushort_t)(u >> 16);
}
__device__ __forceinline__ float bf2f(uint_t lo16) { return __uint_as_float(lo16 << 16); }
__device__ __forceinline__ float leaky(float x) { return x > 0.f ? x : 0.01f * x; }

// ---------------------------------------------------------------------------
// K0: adj f32 -> i8 (round(a*127)) + row sums -> s, rinv.
// Block 0 zeroes the cmax region (replaces the memset dispatch).
__global__ __launch_bounds__(256) void conv_rowsum(const float* __restrict__ adj,
    char* __restrict__ adjq, float* __restrict__ s, float* __restrict__ rinv,
    float* __restrict__ zbase)
{
    const int i = blockIdx.x;
    if (i == 0) {
        ((float4*)zbase)[threadIdx.x] = float4{0.f, 0.f, 0.f, 0.f};  // 1024 floats
    }
    const float4* arow = (const float4*)(adj + ((size_t)i << 13));
    uint_t* brow = (uint_t*)(adjq + ((size_t)i << 13));
    float partial = 0.f;
    for (int t = threadIdx.x; t < 2048; t += 256) {
        const float4 v = arow[t];
        partial += (v.x + v.y) + (v.z + v.w);
        const uint_t q0 = (uint_t)__float2int_rn(v.x * 127.f);
        const uint_t q1 = (uint_t)__float2int_rn(v.y * 127.f);
        const uint_t q2 = (uint_t)__float2int_rn(v.z * 127.f);
        const uint_t q3 = (uint_t)__float2int_rn(v.w * 127.f);
        brow[t] = q0 | (q1 << 8) | (q2 << 16) | (q3 << 24);
    }
    #pragma unroll
    for (int off = 32; off; off >>= 1) partial += __shfl_xor(partial, off);
    __shared__ float ps[4];
    if ((threadIdx.x & 63) == 0) ps[threadIdx.x >> 6] = partial;
    __syncthreads();
    if (threadIdx.x == 0) {
        const float tot = (ps[0] + ps[1]) + (ps[2] + ps[3]);
        s[i]    = rsqrtf(tot + 1.0f);
        rinv[i] = 1.0f / tot;
    }
}

// ---------------------------------------------------------------------------
// K1: per-column max of |b| for level-1 B.
__global__ __launch_bounds__(256) void preMax(const float* __restrict__ u,
    const float* __restrict__ v, const float* __restrict__ s, const float* __restrict__ rinv,
    float* __restrict__ cmax)
{
    const int j0 = (blockIdx.x & 127) << 6;
    const int c0 = (blockIdx.x >> 7) << 6;
    __shared__ uint_t cm[64];
    if (threadIdx.x < 64) cm[threadIdx.x] = 0;
    __syncthreads();
    const int tx = threadIdx.x & 63;
    const int ty = threadIdx.x >> 6;
    float m = 0.f;
    #pragma unroll
    for (int rr = 0; rr < 16; ++rr) {
        const int j = j0 + ty + (rr << 2);
        const int c = c0 + tx;
        const float val = (c < 128) ? s[j] * u[((size_t)j << 7) + c]
                                    : rinv[j] * v[((size_t)j << 7) + (c - 128)];
        m = fmaxf(m, fabsf(val));
    }
    atomicMax(&cm[tx], __float_as_uint(m));
    __syncthreads();
    if (threadIdx.x < 64)
        atomicMax((uint_t*)&cmax[c0 + threadIdx.x], cm[threadIdx.x]);
}

// ---------------------------------------------------------------------------
// K2: build Bi8 with per-column scale 127/cmax[c]; dq[c] = cmax[c]/127^2.
__global__ __launch_bounds__(256) void preQ(const float* __restrict__ u,
    const float* __restrict__ v, const float* __restrict__ s, const float* __restrict__ rinv,
    const float* __restrict__ cmax, char* __restrict__ Bi8, float* __restrict__ dq)
{
    const int j0 = (blockIdx.x & 127) << 6;
    const int c0 = (blockIdx.x >> 7) << 6;
    __shared__ float tile[64][65];
    const int tx = threadIdx.x & 63;
    const int ty = threadIdx.x >> 6;
    #pragma unroll
    for (int rr = 0; rr < 16; ++rr) {
        const int jl = ty + (rr << 2);
        const int j = j0 + jl;
        const int c = c0 + tx;
        tile[jl][tx] = (c < 128) ? s[j] * u[((size_t)j << 7) + c]
                                 : rinv[j] * v[((size_t)j << 7) + (c - 128)];
    }
    __syncthreads();
    const int cl = threadIdx.x & 63;
    const int jq = threadIdx.x >> 6;
    const float cmv = cmax[c0 + cl];
    const float rs = cmv > 0.f ? 127.f / cmv : 0.f;
    uint_t w4[4];
    #pragma unroll
    for (int g = 0; g < 4; ++g) {
        uint_t wv = 0;
        #pragma unroll
        for (int b = 0; b < 4; ++b) {
            int q = __float2int_rn(tile[(jq << 4) + (g << 2) + b][cl] * rs);
            q = q > 127 ? 127 : (q < -127 ? -127 : q);
            wv |= ((uint_t)(q & 0xff)) << (8 * b);
        }
        w4[g] = wv;
    }
    uint4 st; st.x = w4[0]; st.y = w4[1]; st.z = w4[2]; st.w = w4[3];
    *(uint4*)(Bi8 + ((size_t)(c0 + cl) << 13) + j0 + (jq << 4)) = st;
    if ((blockIdx.x & 127) == 0 && threadIdx.x < 64)
        dq[c0 + threadIdx.x] = cmax[c0 + threadIdx.x] * (1.f / 16129.f);
}

// ---------------------------------------------------------------------------
// K3a: ring-4 i8 GEMM (R10-proven). BM=BN=256, BK=64B, 8 waves 2Mx4N,
// 4-deep 32KB slots, 128 KiB LDS.
#define WAITB(S) do {                                         \
    asm volatile("s_waitcnt " S ::: "memory");                \
    __builtin_amdgcn_sched_barrier(0);                        \
    __builtin_amdgcn_s_barrier();                             \
    __builtin_amdgcn_sched_barrier(0);                        \
} while (0)

__global__ __launch_bounds__(512, 2) void gemm_i8(const char* __restrict__ A,
    const char* __restrict__ Bt, ushort_t* __restrict__ Yb)
{
    __shared__ char lds[4 * 32768];       // ring: [4][A 16KB | B 16KB]
    const int bid = blockIdx.x;
    const int mb = bid & 31;
    const int ks = bid >> 5;
    const size_t mBase = (size_t)mb * 256;
    const int tid = threadIdx.x;
    const int w = tid >> 6, l = tid & 63;
    const int wr = w >> 2, wc = w & 3;
    const int frow = l & 15, fk = l >> 4;
    const int fsl = ((fk ^ ((frow >> 1) & 3)) << 4);
    const int srow = l >> 2;
    const int skoff = (((l & 3) ^ ((l >> 3) & 3)) << 4);
    const int kBeg = ks << 10;

    i32x4 acc[8][4] = {};

    auto STAGE = [&](int t) {
        const int k0 = kBeg + (t << 6);
        char* base = &lds[(t & 3) << 15];
        #pragma unroll
        for (int q = 0; q < 2; ++q) {
            const int c = (w << 1) + q;
            const int row = (c << 4) + srow;
            __builtin_amdgcn_global_load_lds(
                (const gbl_void_t*)(A + ((mBase + row) << 13) + k0 + skoff),
                (lds_void_t*)(base + (c << 10)), 16, 0, 0);
            __builtin_amdgcn_global_load_lds(
                (const gbl_void_t*)(Bt + ((size_t)row << 13) + k0 + skoff),
                (lds_void_t*)(base + 16384 + (c << 10)), 16, 0, 0);
        }
    };
    auto COMPUTE = [&](int T) {
        const char* buf = &lds[(T & 3) << 15];
        i32x4 av[8], bv[4];
        #pragma unroll
        for (int mi = 0; mi < 8; ++mi) {
            const int row = (wr << 7) + (mi << 4) + frow;
            av[mi] = *(const i32x4*)(buf + (row << 6) + fsl);
        }
        #pragma unroll
        for (int ni = 0; ni < 4; ++ni) {
            const int col = (wc << 6) + (ni << 4) + frow;
            bv[ni] = *(const i32x4*)(buf + 16384 + (col << 6) + fsl);
        }
        __builtin_amdgcn_s_setprio(1);
        #pragma unroll
        for (int mi = 0; mi < 8; ++mi)
            #pragma unroll
            for (int ni = 0; ni < 4; ++ni)
                acc[mi][ni] = __builtin_amdgcn_mfma_i32_16x16x64_i8(
                    av[mi], bv[ni], acc[mi][ni], 0, 0, 0);
        __builtin_amdgcn_s_setprio(0);
    };

    STAGE(0); STAGE(1); STAGE(2);
    #pragma unroll 1
    for (int T = 0; T < NTQ - 3; ++T) {
        WAITB("vmcnt(8)");
        STAGE(T + 3);
        COMPUTE(T);
    }
    WAITB("vmcnt(8)"); COMPUTE(NTQ - 3);
    WAITB("vmcnt(4)"); COMPUTE(NTQ - 2);
    WAITB("vmcnt(0)"); COMPUTE(NTQ - 1);
    __syncthreads();

    // Epilogue: i32 -> f32 -> bf16 Cs[256][256] -> coalesced stores.
    ushort_t* Cs = (ushort_t*)lds;
    const int orow = (l >> 4) << 2;
    const int ocol = l & 15;
    #pragma unroll
    for (int mi = 0; mi < 8; ++mi) {
        #pragma unroll
        for (int ni = 0; ni < 4; ++ni) {
            const int rl = (wr << 7) + (mi << 4) + orow;
            const int cl = (wc << 6) + (ni << 4) + ocol;
            #pragma unroll
            for (int r = 0; r < 4; ++r)
                Cs[(rl + r) * 256 + cl] = f2bf((float)acc[mi][ni][r]);
        }
    }
    __syncthreads();
    const size_t sliceBase = ((size_t)ks * NN + mBase) * 256;
    #pragma unroll
    for (int p = 0; p < 16; ++p) {
        const int idx16 = (p << 9) + tid;
        const int row   = idx16 >> 5;
        const int c16   = idx16 & 31;
        const uint4 v = *(const uint4*)(&Cs[(row << 8) + (c16 << 3)]);
        *(uint4*)(Yb + sliceBase + (size_t)row * 256 + (c16 << 3)) = v;
    }
}

// ---------------------------------------------------------------------------
// K3b (L4): half-width i8 GEMM. BM=256 BN=128, 4 waves, ring-2 (48KB).
__global__ __launch_bounds__(256, 2) void gemm_half_i8(const char* __restrict__ A,
    const char* __restrict__ Bt, ushort_t* __restrict__ Yb, int nbOff, int nbCount)
{
    __shared__ char lds[2 * 24576];       // per buf: A 16KB | B 8KB
    const int bid  = blockIdx.x;
    const int mb   = bid & 31;
    const int rest = bid >> 5;
    const int nb   = nbOff + (rest % nbCount);
    const int ks   = rest / nbCount;
    const size_t mBase = (size_t)mb * 256;
    const size_t nBase = (size_t)nb * 128;
    const int tid = threadIdx.x;
    const int w = tid >> 6, l = tid & 63;
    const int wr = w >> 1, wc = w & 1;
    const int frow = l & 15, fk = l >> 4;
    const int fsl = ((fk ^ ((frow >> 1) & 3)) << 4);
    const int srow = l >> 2;
    const int skoff = (((l & 3) ^ ((l >> 3) & 3)) << 4);
    const int kBeg = ks << 10;

    i32x4 acc[8][4] = {};

    auto STAGE = [&](int t) {
        const int k0 = kBeg + (t << 6);
        char* base = &lds[(t & 1) * 24576];
        #pragma unroll
        for (int q = 0; q < 4; ++q) {
            const int c = (w << 2) + q;
            const int row = (c << 4) + srow;
            __builtin_amdgcn_global_load_lds(
                (const gbl_void_t*)(A + ((mBase + row) << 13) + k0 + skoff),
                (lds_void_t*)(base + (c << 10)), 16, 0, 0);
        }
        #pragma unroll
        for (int q = 0; q < 2; ++q) {
            const int c = (w << 1) + q;
            const int row = (c << 4) + srow;
            __builtin_amdgcn_global_load_lds(
                (const gbl_void_t*)(Bt + ((nBase + row) << 13) + k0 + skoff),
                (lds_void_t*)(base + 16384 + (c << 10)), 16, 0, 0);
        }
    };

    STAGE(0);
    __syncthreads();
    #pragma unroll 1
    for (int T = 0; T < NTQ; ++T) {
        if (T + 1 < NTQ) STAGE(T + 1);
        const char* buf = &lds[(T & 1) * 24576];
        i32x4 av[8], bv[4];
        #pragma unroll
        for (int mi = 0; mi < 8; ++mi) {
            const int row = (wr << 7) + (mi << 4) + frow;
            av[mi] = *(const i32x4*)(buf + (row << 6) + fsl);
        }
        #pragma unroll
        for (int ni = 0; ni < 4; ++ni) {
            const int col = (wc << 6) + (ni << 4) + frow;
            bv[ni] = *(const i32x4*)(buf + 16384 + (col << 6) + fsl);
        }
        __builtin_amdgcn_s_setprio(1);
        #pragma unroll
        for (int mi = 0; mi < 8; ++mi)
            #pragma unroll
            for (int ni = 0; ni < 4; ++ni)
                acc[mi][ni] = __builtin_amdgcn_mfma_i32_16x16x64_i8(
                    av[mi], bv[ni], acc[mi][ni], 0, 0, 0);
        __builtin_amdgcn_s_setprio(0);
        __syncthreads();
    }

    const int orow = (l >> 4) << 2;
    const int ocol = l & 15;
    const size_t sliceBase = ((size_t)ks * NN + mBase) * 256 + nBase;
    #pragma unroll
    for (int p = 0; p < 2; ++p) {
        __syncthreads();
        ushort_t* Cs = (ushort_t*)lds;     // [128][128] bf16
        #pragma unroll
        for (int mi = 0; mi < 4; ++mi) {
            #pragma unroll
            for (int ni = 0; ni < 4; ++ni) {
                const int rl = (wr << 6) + (mi << 4) + orow;
                const int cl = (wc << 6) + (ni << 4) + ocol;
                #pragma unroll
                for (int r = 0; r < 4; ++r)
                    Cs[(rl + r) * 128 + cl] = f2bf((float)acc[(p << 2) + mi][ni][r]);
            }
        }
        __syncthreads();
        #pragma unroll
        for (int pp = 0; pp < 8; ++pp) {
            const int idx16 = (pp << 8) + tid;
            const int lrow  = idx16 >> 4;
            const int c16   = idx16 & 15;
            const int rowIn = ((lrow >> 6) << 7) + (p << 6) + (lrow & 63);
            const uint4 v = *(const uint4*)(&Cs[(lrow << 7) + (c16 << 3)]);
            *(uint4*)(Yb + sliceBase + (size_t)rowIn * 256 + (c16 << 3)) = v;
        }
    }
}

// ---------------------------------------------------------------------------
// K4: reduce KS bf16 partials, dequant by dq[c], postscale; track next-level
// per-column max into cmaxN (L1-3).
__global__ __launch_bounds__(256) void reduce_post(const ushort_t* __restrict__ Yb,
    const float* __restrict__ u, const float* __restrict__ v,
    const float* __restrict__ s, const float* __restrict__ rinv,
    float* __restrict__ hop_out, float* __restrict__ walk_out,
    const float* __restrict__ dq, float* __restrict__ cmaxN, int c0Off)
{
    const int j0 = (blockIdx.x & 127) << 6;
    const int c0 = ((blockIdx.x >> 7) + c0Off) << 6;
    const bool hop = (c0 < 128);
    if (hop && hop_out == nullptr) return;
    __shared__ uint_t cm[64];
    if (cmaxN && threadIdx.x < 64) cm[threadIdx.x] = 0;
    if (cmaxN) __syncthreads();
    const int cg = threadIdx.x & 15;
    const int jr = threadIdx.x >> 4;
    const size_t SL = (size_t)NN * 256;
    const float4 dqv = ((const float4*)dq)[(c0 >> 2) + cg];
    float lm0 = 0.f, lm1 = 0.f, lm2 = 0.f, lm3 = 0.f;
    #pragma unroll
    for (int it = 0; it < 4; ++it) {
        const int jl = jr + (it << 4);
        const int j  = j0 + jl;
        const int c  = c0 + (cg << 2);
        const ushort_t* p = Yb + ((size_t)j << 8) + c;
        float e0 = 0.f, e1 = 0.f, e2 = 0.f, e3 = 0.f;
        #pragma unroll
        for (int kss = 0; kss < KS; ++kss) {
            const uint2 q = *(const uint2*)(p + kss * SL);
            e0 += bf2f(q.x & 0xffffu);
            e1 += __uint_as_float(q.x & 0xffff0000u);
            e2 += bf2f(q.y & 0xffffu);
            e3 += __uint_as_float(q.y & 0xffff0000u);
        }
        e0 *= dqv.x; e1 *= dqv.y; e2 *= dqv.z; e3 *= dqv.w;
        float4 o; float scale;
        if (hop) {
            const float si = s[j], si2 = si * si;
            const float4 uu = ((const float4*)u)[((size_t)j << 5) + (c >> 2)];
            o.x = si * e0 + si2 * uu.x;  o.y = si * e1 + si2 * uu.y;
            o.z = si * e2 + si2 * uu.z;  o.w = si * e3 + si2 * uu.w;
            ((float4*)hop_out)[((size_t)j << 5) + (c >> 2)] = o;
            scale = si;
        } else {
            const int cw = c - 128;
            const float4 vv = ((const float4*)v)[((size_t)j << 5) + (cw >> 2)];
            o.x = 0.5f * (vv.x + e0);  o.y = 0.5f * (vv.y + e1);
            o.z = 0.5f * (vv.z + e2);  o.w = 0.5f * (vv.w + e3);
            ((float4*)walk_out)[((size_t)j << 5) + (cw >> 2)] = o;
            scale = rinv[j];
        }
        if (cmaxN) {
            lm0 = fmaxf(lm0, fabsf(scale * o.x));
            lm1 = fmaxf(lm1, fabsf(scale * o.y));
            lm2 = fmaxf(lm2, fabsf(scale * o.z));
            lm3 = fmaxf(lm3, fabsf(scale * o.w));
        }
    }
    if (cmaxN) {
        atomicMax(&cm[(cg << 2) + 0], __float_as_uint(lm0));
        atomicMax(&cm[(cg << 2) + 1], __float_as_uint(lm1));
        atomicMax(&cm[(cg << 2) + 2], __float_as_uint(lm2));
        atomicMax(&cm[(cg << 2) + 3], __float_as_uint(lm3));
        __syncthreads();
        if (threadIdx.x < 64)
            atomicMax((uint_t*)&cmaxN[c0 + threadIdx.x], cm[threadIdx.x]);
    }
}

// ---------------------------------------------------------------------------
// K5: fused attn + inline L4 reduce + 2-layer MLP. 16 nodes/block,
// 16 thr/node (8 k's each). p4x computed inline from Yb walk columns
// (same kss order as old reduce4 -> bit-identical). W1 then W2 staged into
// the same 67.6KB Ws region; Hs holds attn output then mid activations.
// 76 KB LDS -> 2 blocks/CU.
__global__ __launch_bounds__(256) void attn_mlp(const float* __restrict__ X,
    const float* __restrict__ hA, const float* __restrict__ hA2, const float* __restrict__ hA3,
    const float* __restrict__ px, const float* __restrict__ p2x, const float* __restrict__ p3x,
    const ushort_t* __restrict__ Yb, const float* __restrict__ dq,
    const float* __restrict__ a, const float* __restrict__ W1, const float* __restrict__ b1,
    const float* __restrict__ W2, const float* __restrict__ b2, float* __restrict__ out)
{
    __shared__ float Ws[128 * 132];
    __shared__ float Hs[16 * 132];
    const int tid = threadIdx.x;
    const int node0 = blockIdx.x << 4;
    const int n = tid >> 4, c = tid & 15;
    // stage W1 (attn compute below hides the load latency)
    for (int rr = 0; rr < 64; ++rr) {
        const int idx = rr * 256 + tid;
        Ws[(idx >> 7) * 132 + (idx & 127)] = W1[idx];
    }
    // ---- inline L4 reduce for this thread's 8 k's ----
    const size_t i = (size_t)(node0 + n);
    const size_t base = i << 7;
    const int k0 = c << 3;
    const size_t SL = (size_t)NN * 256;
    float ew[8] = {};
    const ushort_t* yp = Yb + (i << 8) + 128 + k0;
    #pragma unroll
    for (int kss = 0; kss < KS; ++kss) {
        const uint4 q = *(const uint4*)(yp + kss * SL);
        ew[0] += bf2f(q.x & 0xffffu);  ew[1] += __uint_as_float(q.x & 0xffff0000u);
        ew[2] += bf2f(q.y & 0xffffu);  ew[3] += __uint_as_float(q.y & 0xffff0000u);
        ew[4] += bf2f(q.z & 0xffffu);  ew[5] += __uint_as_float(q.z & 0xffff0000u);
        ew[6] += bf2f(q.w & 0xffffu);  ew[7] += __uint_as_float(q.w & 0xffff0000u);
    }
    // ---- attention ----
    float f[6][8];
    float e[6] = {0.f, 0.f, 0.f, 0.f, 0.f, 0.f};
    #pragma unroll
    for (int h = 0; h < 8; ++h) {
        const int k = k0 + h;
        const float a2 = a[128 + k];
        const float x   = X[base + k];
        const float t1  = leaky(hA [base + k]);
        const float t2  = leaky(hA2[base + k]);
        const float t3  = leaky(hA3[base + k]);
        const float pk  = px [base + k];
        const float p2k = p2x[base + k];
        const float p4k = 0.5f * (p3x[base + k] + ew[h] * dq[128 + k]);
        const float s1 = fabsf(x - pk);
        const float s2 = fabsf(pk - p2k);
        const float s3 = fabsf(p2k - p4k);
        f[0][h] = t1; f[1][h] = t2; f[2][h] = t3;
        f[3][h] = s1; f[4][h] = s2; f[5][h] = s3;
        e[0] += fmaxf(t1, 0.f) * a2;
        e[1] += fmaxf(t2, 0.f) * a2;
        e[2] += fmaxf(t3, 0.f) * a2;
        e[3] += s1 * a2;
        e[4] += s2 * a2;
        e[5] += s3 * a2;
    }
    #pragma unroll
    for (int ss = 0; ss < 6; ++ss) {
        #pragma unroll
        for (int off = 8; off; off >>= 1) e[ss] += __shfl_xor(e[ss], off);
    }
    float mx = e[0];
    #pragma unroll
    for (int ss = 1; ss < 6; ++ss) mx = fmaxf(mx, e[ss]);
    float at[6], sum = 0.f;
    #pragma unroll
    for (int ss = 0; ss < 6; ++ss) { at[ss] = expf(e[ss] - mx); sum += at[ss]; }
    const float inv = 1.f / (6.f * sum);
    #pragma unroll
    for (int h = 0; h < 8; ++h) {
        float o = 0.f;
        #pragma unroll
        for (int ss = 0; ss < 6; ++ss) o += at[ss] * f[ss][h];
        Hs[n * 132 + k0 + h] = o * inv;
    }
    __syncthreads();
    // ---- MLP layer 1 ----
    float acc[8] = {};
    for (int k4 = 0; k4 < 32; ++k4) {
        const float4 h4 = *(const float4*)(&Hs[n * 132 + (k4 << 2)]);
        #pragma unroll
        for (int r = 0; r < 8; ++r) {
            const float4 w4 = *(const float4*)(&Ws[(c + (r << 4)) * 132 + (k4 << 2)]);
            acc[r] += h4.x * w4.x + h4.y * w4.y + h4.z * w4.z + h4.w * w4.w;
        }
    }
    __syncthreads();            // all layer-1 reads of Hs/Ws complete
    #pragma unroll
    for (int r = 0; r < 8; ++r) {
        const int o = c + (r << 4);
        Hs[n * 132 + o] = leaky(acc[r] + b1[o]);
    }
    for (int rr = 0; rr < 64; ++rr) {     // stage W2 over W1
        const int idx = rr * 256 + tid;
        Ws[(idx >> 7) * 132 + (idx & 127)] = W2[idx];
    }
    __syncthreads();
    // ---- MLP layer 2 ----
    float acc2[8] = {};
    for (int k4 = 0; k4 < 32; ++k4) {
        const float4 h4 = *(const float4*)(&Hs[n * 132 + (k4 << 2)]);
        #pragma unroll
        for (int r = 0; r < 8; ++r) {
            const float4 w4 = *(const float4*)(&Ws[(c + (r << 4)) * 132 + (k4 << 2)]);
            acc2[r] += h4.x * w4.x + h4.y * w4.y + h4.z * w4.z + h4.w * w4.w;
        }
    }
    #pragma unroll
    for (int r = 0; r < 8; ++r) {
        const int o = c + (r << 4);
        out[base + o] = leaky(acc2[r] + b2[o]);
    }
}

// ---------------------------------------------------------------------------
extern "C" void kernel_launch(void* const* d_in, const int* in_sizes, int n_in,
                              void* d_out, int out_size, void* d_ws, size_t ws_size,
                              hipStream_t stream)
{
    const float* X   = (const float*)d_in[0];
    const float* adj = (const float*)d_in[1];
    const float* W1  = (const float*)d_in[2];
    const float* b1  = (const float*)d_in[3];
    const float* W2  = (const float*)d_in[4];
    const float* b2  = (const float*)d_in[5];
    const float* a   = (const float*)d_in[6];
    float* out = (float*)d_out;

    // Workspace layout (~132 MB)
    char* ws = (char*)d_ws;
    char*     adjq = ws;                                   //  64 MB i8 adj
    char*     Bi8  = ws + 67108864ull;                     //   2 MB i8 B
    ushort_t* Yb   = (ushort_t*)(ws + 69206016ull);        //  32 MB bf16 partials
    float* hA  = (float*)(ws + 102760448ull);              //   4 MB each below
    float* hA2 = hA  + 1048576;
    float* hA3 = hA2 + 1048576;
    float* px  = hA3 + 1048576;
    float* p2x = px  + 1048576;
    float* p3x = p2x + 1048576;
    float* sbuf  = p3x + 1048576;                          // 32 KB
    float* rinvb = sbuf + 8192;                            // 32 KB
    float* cmaxb = rinvb + 8192;                           // 4 x 256 f32
    float* dq    = cmaxb + 1024;                           // 256 f32
    float* cmax1 = cmaxb, *cmax2 = cmaxb + 256, *cmax3 = cmaxb + 512, *cmax4 = cmaxb + 768;

    conv_rowsum<<<8192, 256, 0, stream>>>(adj, adjq, sbuf, rinvb, cmaxb);

    // Level 1
    preMax<<<512, 256, 0, stream>>>(X, X, sbuf, rinvb, cmax1);
    preQ  <<<512, 256, 0, stream>>>(X, X, sbuf, rinvb, cmax1, Bi8, dq);
    gemm_i8<<<256, 512, 0, stream>>>(adjq, Bi8, Yb);
    reduce_post<<<512, 256, 0, stream>>>(Yb, X, X, sbuf, rinvb,
                                         hA, px, dq, cmax2, 0);
    // Level 2
    preQ  <<<512, 256, 0, stream>>>(hA, px, sbuf, rinvb, cmax2, Bi8, dq);
    gemm_i8<<<256, 512, 0, stream>>>(adjq, Bi8, Yb);
    reduce_post<<<512, 256, 0, stream>>>(Yb, hA, px, sbuf, rinvb,
                                         hA2, p2x, dq, cmax3, 0);
    // Level 3
    preQ  <<<512, 256, 0, stream>>>(hA2, p2x, sbuf, rinvb, cmax3, Bi8, dq);
    gemm_i8<<<256, 512, 0, stream>>>(adjq, Bi8, Yb);
    reduce_post<<<512, 256, 0, stream>>>(Yb, hA2, p2x, sbuf, rinvb,
                                         hA3, p3x, dq, cmax4, 0);
    // Level 4 (walk half only; reduce folded into attn_mlp)
    preQ  <<<512, 256, 0, stream>>>(hA3, p3x, sbuf, rinvb, cmax4, Bi8, dq);
    gemm_half_i8<<<256, 256, 0, stream>>>(adjq, Bi8, Yb, 1, 1);

    attn_mlp<<<512, 256, 0, stream>>>(X, hA, hA2, hA3, px, p2x, p3x,
                                      Yb, dq, a, W1, b1, W2, b2, out);
}